// Round 14
// baseline (226.964 us; speedup 1.0000x reference)
//
#include <hip/hip_runtime.h>
#include <hip/hip_bf16.h>

typedef __hip_bfloat16 bf16;
typedef unsigned short u16;
typedef unsigned int u32;
typedef __attribute__((ext_vector_type(8))) short bf16x8;
typedef __attribute__((ext_vector_type(4))) float f32x4;

#define BB 4
#define CCH 32
#define HH 64
#define WW 64
#define NN 4096
#define D 288
#define DR 144
#define DQ 432
#define NH 8
#define HD 18
#define SPLIT 4
#define CHUNK 1024
#define KS 512        // keys per split-K slice
#define DH 72
#define SCALE_ 0.16666666666666666f
#define QSCALE 0.24044917348149343f   // SCALE_ * log2(e): softmax via exp2
#define EPS_ 1e-5f
#define ASTR 160
#define HSTR 96

// ---- static device workspace (.bss zeros; pad regions stay zero except vt row 18 = 1.0)
__device__ __attribute__((aligned(16))) u16 g_Wcb[DQ * D];
__device__ __attribute__((aligned(16))) u16 g_pw[D * ASTR];
__device__ __attribute__((aligned(16))) u16 g_f1w[HSTR * D];
__device__ __attribute__((aligned(16))) u16 g_f2w[D * HSTR];
__device__ __attribute__((aligned(16))) u16 g_q[(size_t)BB * NH * NN * 32];
__device__ __attribute__((aligned(16))) u16 g_k[(size_t)BB * NH * NN * 32];
__device__ __attribute__((aligned(16))) u16 g_vt[(size_t)BB * NH * SPLIT * 32 * CHUNK];
__device__ __attribute__((aligned(16))) float g_part[2 * (size_t)BB * NH * NN * 20]; // split-K partials
__device__ __attribute__((aligned(16))) u16 g_attn[(size_t)BB * NN * ASTR];
__device__ __attribute__((aligned(16))) u16 g_h[(size_t)BB * NN * HSTR];
__device__ __attribute__((aligned(16))) u16 g_t0[(size_t)BB * NN * D];
__device__ __attribute__((aligned(16))) u16 g_t1[(size_t)BB * NN * D];   // bf16 residual stream
__device__ float g_t2[(size_t)BB * D * NN];
__device__ int   g_flag;

__device__ __forceinline__ float b2f(bf16 v) { return __bfloat162float(v); }
__device__ __forceinline__ float bits2f(u16 u) { return __uint_as_float(((u32)u) << 16); }
__device__ __forceinline__ u16 f2bits(float f) {
    u32 u = __float_as_uint(f);
    return (u16)((u + 0x7FFF + ((u >> 16) & 1)) >> 16);   // RNE
}
__device__ __forceinline__ float ldin(const void* p, size_t i, int isbf) {
    return isbf ? b2f(((const bf16*)p)[i]) : ((const float*)p)[i];
}

#define RS  (D * ASTR + HSTR * D + D * HSTR)      // staging elems 101376
#define RS2 (RS + BB * NH * SPLIT * CHUNK)        // + vt ones-row fills = 232448
#define RSB ((RS2 + 255) / 256)                   // 908
#define PATCHB (BB * HH)                          // 256 patch blocks

// ---- prep: dtype detect + Wc GEMM + weight staging + vt ones row + patch extract
__global__ void k_prep(const void* __restrict__ x, const void* __restrict__ qkv_w,
                       const void* __restrict__ reduce_w, const void* __restrict__ proj_w,
                       const void* __restrict__ fc1_w, const void* __restrict__ fc2_w) {
    __shared__ int cnt4[4];
    __shared__ float qw[DR];
    __shared__ float slab[32 * 3 * 66];
    int tid = threadIdx.x;
    {
        const u16* u = (const u16*)x;
        int c = 0;
        for (int i = tid; i < 2048; i += 256) c += (((u[i] >> 7) & 0xFF) >= 0x90);
        for (int o = 32; o; o >>= 1) c += __shfl_xor(c, o);
        if ((tid & 63) == 0) cnt4[tid >> 6] = c;
    }
    __syncthreads();
    int bf = (cnt4[0] + cnt4[1] + cnt4[2] + cnt4[3]) < 32;
    if (tid == 0 && blockIdx.x == 0) g_flag = bf;

    int bid = blockIdx.x;
    if (bid < DQ) {
        int o = bid;
        if (tid < DR) qw[tid] = ldin(qkv_w, (size_t)o * DR + tid, bf);
        __syncthreads();
        for (int col = tid; col < D; col += 256) {
            float s0 = 0.f, s1 = 0.f;
            #pragma unroll 4
            for (int j = 0; j < DR; j += 2) {
                s0 += qw[j] * ldin(reduce_w, (size_t)j * D + col, bf);
                s1 += qw[j + 1] * ldin(reduce_w, (size_t)(j + 1) * D + col, bf);
            }
            g_Wcb[(size_t)o * D + col] = f2bits(s0 + s1);
        }
    } else if (bid < DQ + RSB) {
        int idx = (bid - DQ) * 256 + tid;
        if (idx < D * ASTR) {
            int o = idx / ASTR, j = idx % ASTR;
            g_pw[idx] = (j < DR) ? f2bits(ldin(proj_w, (size_t)o * DR + j, bf)) : (u16)0;
        } else if (idx < D * ASTR + HSTR * D) {
            int t = idx - D * ASTR;
            int o = t / D;
            g_f1w[t] = (o < DH) ? f2bits(ldin(fc1_w, (size_t)t, bf)) : (u16)0;
        } else if (idx < RS) {
            int t = idx - D * ASTR - HSTR * D;
            int o = t / HSTR, j = t % HSTR;
            g_f2w[t] = (j < DH) ? f2bits(ldin(fc2_w, (size_t)o * DH + j, bf)) : (u16)0;
        } else if (idx < RS2) {
            // V^T row 18 := 1.0 -> PV MFMA computes row-sum l at dim 18
            int t = idx - RS;
            int bhs = t >> 10, n = t & 1023;
            g_vt[((size_t)bhs * 32 + 18) * CHUNK + n] = 0x3F80;  // bf16 1.0
        }
    } else {
        // patch extract: block = (b, y)
        int pb = bid - DQ - RSB;
        int b = pb >> 6, y = pb & 63;
        for (int idx = tid; idx < 32 * 3 * 66; idx += 256) {
            int c = idx / 198, rem = idx % 198;
            int ki = rem / 66, col = rem % 66 - 1;
            int sy = y + ki - 1;
            float v = 0.f;
            if (col >= 0 && col < 64 && sy >= 0 && sy < 64)
                v = ldin(x, ((size_t)(b * CCH + c) * HH + sy) * WW + col, bf);
            slab[idx] = v;
        }
        __syncthreads();
        size_t obase = ((size_t)b * NN + y * 64) * D;
        for (int idx = tid; idx < 64 * D; idx += 256) {
            int t = idx / D, f = idx % D;
            int c = f / 9, k = f % 9, ki = k / 3, kj = k % 3;
            g_t0[obase + idx] = f2bits(slab[c * 198 + ki * 66 + t + kj]);
        }
    }
}

// ---- LN1 + qkv GEMM; block = 16 tokens; V staged through LDS (coalesced out)
__global__ void k_ln_qkv(const void* __restrict__ lnw, const void* __restrict__ lnb) {
    __shared__ __attribute__((aligned(16))) u16 xln[16 * 296];
    __shared__ float lnwf[D], lnbf[D];
    __shared__ float smu[16], srs[16];
    __shared__ u16 vbuf[144][18];
    int bf = g_flag;
    int tid = threadIdx.x;
    size_t tok0 = (size_t)blockIdx.x * 16;
    for (int i = tid; i < D; i += 256) { lnwf[i] = ldin(lnw, i, bf); lnbf[i] = ldin(lnb, i, bf); }
    {
        int tt = tid >> 4, p = tid & 15;
        const u32* pr = (const u32*)(g_t0 + (tok0 + tt) * D + p * 18);
        float s = 0.f, q = 0.f;
        #pragma unroll
        for (int j = 0; j < 9; ++j) {
            u32 v = pr[j];
            float a = bits2f((u16)(v & 0xFFFF)), b = bits2f((u16)(v >> 16));
            s += a + b; q += a * a + b * b;
        }
        #pragma unroll
        for (int o = 1; o < 16; o <<= 1) { s += __shfl_xor(s, o); q += __shfl_xor(q, o); }
        if (p == 0) {
            float mu = s / D;
            smu[tt] = mu;
            srs[tt] = rsqrtf(q / D - mu * mu + EPS_);
        }
    }
    __syncthreads();
    for (int idx = tid; idx < 16 * 144; idx += 256) {
        int t = idx / 144, dw = idx % 144;
        u32 v = *(const u32*)(g_t0 + (tok0 + t) * D + 2 * dw);
        float mu = smu[t], rs = srs[t];
        int f = 2 * dw;
        float a = (bits2f((u16)(v & 0xFFFF)) - mu) * rs * lnwf[f] + lnbf[f];
        float b = (bits2f((u16)(v >> 16)) - mu) * rs * lnwf[f + 1] + lnbf[f + 1];
        *(u32*)&xln[t * 296 + f] = (u32)f2bits(a) | ((u32)f2bits(b) << 16);
    }
    __syncthreads();
    int w = tid >> 6, lane = tid & 63, quad = lane >> 4, l15 = lane & 15;
    bf16x8 areg[9];
    const u16* abase = xln + l15 * 296 + quad * 8;
    #pragma unroll
    for (int ks = 0; ks < 9; ++ks) areg[ks] = *(const bf16x8*)(abase + ks * 32);
    int nt0 = w * 7, nt1 = (nt0 + 7 > 27) ? 27 : nt0 + 7;
    for (int nt = nt0; nt < nt1; ++nt) {
        f32x4 acc = {0.f, 0.f, 0.f, 0.f};
        const u16* bbase = g_Wcb + (size_t)(nt * 16 + l15) * D + quad * 8;
        #pragma unroll
        for (int ks = 0; ks < 9; ++ks) {
            bf16x8 bfr = *(const bf16x8*)(bbase + ks * 32);
            acc = __builtin_amdgcn_mfma_f32_16x16x32_bf16(areg[ks], bfr, acc, 0, 0, 0);
        }
        int o = nt * 16 + l15;
        int which = o / DR, rem = o % DR, hh = rem / HD, dd = rem % HD;
        #pragma unroll
        for (int r = 0; r < 4; ++r) {
            size_t token = tok0 + quad * 4 + r;
            int b_ = (int)(token >> 12), n = (int)(token & 4095);
            size_t row = (size_t)(b_ * NH + hh) * NN + n;
            if (which == 0)      g_q[row * 32 + dd] = f2bits(acc[r] * QSCALE);
            else if (which == 1) g_k[row * 32 + dd] = f2bits(acc[r]);
            else                 vbuf[rem][quad * 4 + r] = f2bits(acc[r]);
        }
    }
    __syncthreads();
    {
        int b_ = (int)(tok0 >> 12);
        int n0 = (int)(tok0 & 4095);
        int sIdx = n0 >> 10, nc = n0 & 1023;
        for (int idx = tid; idx < 144 * 16; idx += 256) {
            int rem = idx >> 4, t = idx & 15;
            int hh = rem / HD, dd = rem % HD;
            size_t voff = (((size_t)(b_ * NH + hh) * SPLIT + sIdx) * 32 + dd) * CHUNK + nc + t;
            g_vt[voff] = vbuf[rem][t];
        }
    }
}

// ---- MFMA flash attention, 2-way split-K: 2048 blocks (8/CU), fp32 partials
#define PSTR 72
__global__ __launch_bounds__(128) void k_attn() {
    __shared__ __attribute__((aligned(16))) u16 Pl[2][4][16 * PSTR];  // 18.4 KB
    int bid = blockIdx.x;
    int chunk = bid & 127;              // chunk low -> XCD pinning (both kslices same XCD)
    int qblk = (bid >> 7) & 7;
    int ksl = bid >> 10;                // 0 / 1: key slice
    int s = chunk & 3, bh = chunk >> 2;
    int tid = threadIdx.x;
    int w = tid >> 6, lane = tid & 63, quad = lane >> 4, l15 = lane & 15;

    size_t rowbase = (size_t)bh * NN + s * CHUNK;
    size_t vtbase = ((size_t)bh * SPLIT + s) * 32 * CHUNK;
    const u16* kbase = g_k + rowbase * 32 + quad * 8;
    const u16* vbase = g_vt + vtbase + quad * 8;

    int qbase = qblk * 128 + w * 64;    // token within chunk
    bf16x8 qf[4];
    #pragma unroll
    for (int t = 0; t < 4; ++t)
        qf[t] = *(const bf16x8*)(g_q + (rowbase + qbase + t * 16 + l15) * 32 + quad * 8);

    f32x4 accA[4], accB[4];
    #pragma unroll
    for (int t = 0; t < 4; ++t) {
        accA[t] = (f32x4){0.f, 0.f, 0.f, 0.f};
        accB[t] = (f32x4){0.f, 0.f, 0.f, 0.f};
    }

    int kt0 = ksl * KS;
    for (int kk = 0; kk < KS; kk += 64) {
        int kt = kt0 + kk;
        bf16x8 kf0 = *(const bf16x8*)(kbase + (size_t)(kt + 2 * l15) * 32);
        bf16x8 kf1 = *(const bf16x8*)(kbase + (size_t)(kt + 2 * l15 + 1) * 32);
        bf16x8 kf2 = *(const bf16x8*)(kbase + (size_t)(kt + 32 + 2 * l15) * 32);
        bf16x8 kf3 = *(const bf16x8*)(kbase + (size_t)(kt + 33 + 2 * l15) * 32);
        bf16x8 vA0 = *(const bf16x8*)(vbase + (size_t)l15 * CHUNK + kt);
        bf16x8 vB0 = *(const bf16x8*)(vbase + (size_t)(16 + l15) * CHUNK + kt);
        bf16x8 vA1 = *(const bf16x8*)(vbase + (size_t)l15 * CHUNK + kt + 32);
        bf16x8 vB1 = *(const bf16x8*)(vbase + (size_t)(16 + l15) * CHUNK + kt + 32);
        f32x4 z = {0.f, 0.f, 0.f, 0.f};
        // phase 1: scores + exp2 + perm-packed P stores
        #pragma unroll
        for (int t = 0; t < 4; ++t) {
            u16* pw = Pl[w][t];
            f32x4 S0 = __builtin_amdgcn_mfma_f32_16x16x32_bf16(qf[t], kf0, z, 0, 0, 0);
            f32x4 S1 = __builtin_amdgcn_mfma_f32_16x16x32_bf16(qf[t], kf1, z, 0, 0, 0);
            f32x4 S2 = __builtin_amdgcn_mfma_f32_16x16x32_bf16(qf[t], kf2, z, 0, 0, 0);
            f32x4 S3 = __builtin_amdgcn_mfma_f32_16x16x32_bf16(qf[t], kf3, z, 0, 0, 0);
            #pragma unroll
            for (int r = 0; r < 4; ++r) {
                float p0 = exp2f(S0[r]), p1 = exp2f(S1[r]);
                float p2 = exp2f(S2[r]), p3 = exp2f(S3[r]);
                u32 w0 = __builtin_amdgcn_perm(__float_as_uint(p1), __float_as_uint(p0), 0x07060302u);
                u32 w1 = __builtin_amdgcn_perm(__float_as_uint(p3), __float_as_uint(p2), 0x07060302u);
                *(u32*)&pw[(quad * 4 + r) * PSTR + 2 * l15] = w0;
                *(u32*)&pw[(quad * 4 + r) * PSTR + 32 + 2 * l15] = w1;
            }
        }
        // phase 2: PV (V frags reused 4x); dim 18 of accB accumulates row-sum l
        #pragma unroll
        for (int t = 0; t < 4; ++t) {
            const u16* pw = Pl[w][t];
            bf16x8 pf0 = *(const bf16x8*)&pw[l15 * PSTR + quad * 8];
            bf16x8 pf1 = *(const bf16x8*)&pw[l15 * PSTR + 32 + quad * 8];
            accA[t] = __builtin_amdgcn_mfma_f32_16x16x32_bf16(pf0, vA0, accA[t], 0, 0, 0);
            accB[t] = __builtin_amdgcn_mfma_f32_16x16x32_bf16(pf0, vB0, accB[t], 0, 0, 0);
            accA[t] = __builtin_amdgcn_mfma_f32_16x16x32_bf16(pf1, vA1, accA[t], 0, 0, 0);
            accB[t] = __builtin_amdgcn_mfma_f32_16x16x32_bf16(pf1, vB1, accB[t], 0, 0, 0);
        }
    }
    // write fp32 partials: [ksl][bh][s][tokenc][20]
    float* pb = g_part + (((size_t)ksl * 32 + bh) * SPLIT + s) * (size_t)(CHUNK * 20);
    #pragma unroll
    for (int t = 0; t < 4; ++t) {
        #pragma unroll
        for (int r = 0; r < 4; ++r) {
            int tokenc = qbase + t * 16 + quad * 4 + r;
            float* row = pb + (size_t)tokenc * 20;
            row[l15] = accA[t][r];                     // dims 0-15
            if (l15 < 3) row[16 + l15] = accB[t][r];   // dims 16,17 + l at slot 18
        }
    }
}

// ---- split-K combine: O = (O1+O2)/(l1+l2) -> bf16 g_attn
__global__ void k_comb() {
    int bid = blockIdx.x;               // grid 512
    int chunk = bid & 127, quarter = bid >> 7;
    int s = chunk & 3, bh = chunk >> 2;
    int b = bh >> 3, h = bh & 7;
    int tokenc = quarter * 256 + threadIdx.x;
    const float* p1 = g_part + (((size_t)bh) * SPLIT + s) * (size_t)(CHUNK * 20) + (size_t)tokenc * 20;
    const float* p2 = p1 + (size_t)32 * SPLIT * CHUNK * 20;
    float inv = 1.f / (p1[18] + p2[18]);
    int token = s * CHUNK + tokenc;
    size_t rowoff = ((size_t)b * NN + token) * ASTR + h * HD;
    #pragma unroll
    for (int d = 0; d < HD; ++d)
        g_attn[rowoff + d] = f2bits((p1[d] + p2[d]) * inv);
}

// ---- fused proj + residual + LN2 + fc1 + relu; block = 16 tokens
__global__ void k_proj_ln_fc1(const void* __restrict__ proj_b, const void* __restrict__ lnw,
                              const void* __restrict__ lnb, const void* __restrict__ fc1_b) {
    __shared__ float t1f[16][290];
    __shared__ __attribute__((aligned(16))) u16 xln[16 * 296];
    __shared__ float lnwf[D], lnbf[D];
    __shared__ float smu[16], srs[16];
    int bf = g_flag;
    int tid = threadIdx.x;
    size_t tok0 = (size_t)blockIdx.x * 16;
    int w = tid >> 6, lane = tid & 63, quad = lane >> 4, l15 = lane & 15;
    for (int i = tid; i < D; i += 256) { lnwf[i] = ldin(lnw, i, bf); lnbf[i] = ldin(lnb, i, bf); }

    {
        bf16x8 areg[5];
        const u16* abase = g_attn + (tok0 + l15) * ASTR + quad * 8;
        #pragma unroll
        for (int ks = 0; ks < 5; ++ks) areg[ks] = *(const bf16x8*)(abase + ks * 32);
        const int tab[5] = {0, 5, 10, 14, 18};
        for (int nt = tab[w]; nt < tab[w + 1]; ++nt) {
            f32x4 acc = {0.f, 0.f, 0.f, 0.f};
            const u16* bbase = g_pw + (size_t)(nt * 16 + l15) * ASTR + quad * 8;
            #pragma unroll
            for (int ks = 0; ks < 5; ++ks) {
                bf16x8 bfr = *(const bf16x8*)(bbase + ks * 32);
                acc = __builtin_amdgcn_mfma_f32_16x16x32_bf16(areg[ks], bfr, acc, 0, 0, 0);
            }
            int o = nt * 16 + l15;
            float bias = ldin(proj_b, o, bf);
            #pragma unroll
            for (int r = 0; r < 4; ++r) {
                size_t token = tok0 + quad * 4 + r;
                size_t off = token * D + o;
                float val = bits2f(g_t0[off]) + acc[r] + bias;
                g_t1[off] = f2bits(val);
                t1f[quad * 4 + r][o] = val;
            }
        }
    }
    __syncthreads();
    {
        int tt = tid >> 4, p = tid & 15;
        const float* src = &t1f[tt][p * 18];
        float s = 0.f, q = 0.f;
        #pragma unroll
        for (int j = 0; j < 18; ++j) { float a = src[j]; s += a; q += a * a; }
        #pragma unroll
        for (int o = 1; o < 16; o <<= 1) { s += __shfl_xor(s, o); q += __shfl_xor(q, o); }
        if (p == 0) {
            float mu = s / D;
            smu[tt] = mu;
            srs[tt] = rsqrtf(q / D - mu * mu + EPS_);
        }
    }
    __syncthreads();
    for (int idx = tid; idx < 16 * 144; idx += 256) {
        int t = idx / 144, dw = idx % 144;
        int f = 2 * dw;
        float mu = smu[t], rs = srs[t];
        float a = (t1f[t][f] - mu) * rs * lnwf[f] + lnbf[f];
        float b = (t1f[t][f + 1] - mu) * rs * lnwf[f + 1] + lnbf[f + 1];
        *(u32*)&xln[t * 296 + f] = (u32)f2bits(a) | ((u32)f2bits(b) << 16);
    }
    __syncthreads();
    {
        bf16x8 areg[9];
        const u16* abase = xln + l15 * 296 + quad * 8;
        #pragma unroll
        for (int ks = 0; ks < 9; ++ks) areg[ks] = *(const bf16x8*)(abase + ks * 32);
        const int tab2[5] = {0, 2, 4, 5, 6};
        for (int nt = tab2[w]; nt < tab2[w + 1]; ++nt) {
            f32x4 acc = {0.f, 0.f, 0.f, 0.f};
            const u16* bbase = g_f1w + (size_t)(nt * 16 + l15) * D + quad * 8;
            #pragma unroll
            for (int ks = 0; ks < 9; ++ks) {
                bf16x8 bfr = *(const bf16x8*)(bbase + ks * 32);
                acc = __builtin_amdgcn_mfma_f32_16x16x32_bf16(areg[ks], bfr, acc, 0, 0, 0);
            }
            int o = nt * 16 + l15;
            float bias = (o < DH) ? ldin(fc1_b, o, bf) : 0.f;
            #pragma unroll
            for (int r = 0; r < 4; ++r) {
                size_t token = tok0 + quad * 4 + r;
                g_h[token * HSTR + o] = f2bits(fmaxf(acc[r] + bias, 0.f));
            }
        }
    }
}

// ---- fc2 + residual -> g_t2 transposed via LDS (64B-segment stores)
__global__ void k_fc2(const void* __restrict__ fc2_b) {
    __shared__ float t2f[16][293];   // stride 293: conflict-free transpose read
    int bf = g_flag;
    int tid = threadIdx.x;
    size_t tok0 = (size_t)blockIdx.x * 16;
    int w = tid >> 6, lane = tid & 63, quad = lane >> 4, l15 = lane & 15;
    bf16x8 areg[3];
    const u16* abase = g_h + (tok0 + l15) * HSTR + quad * 8;
    #pragma unroll
    for (int ks = 0; ks < 3; ++ks) areg[ks] = *(const bf16x8*)(abase + ks * 32);
    const int tab[5] = {0, 5, 10, 14, 18};
    for (int nt = tab[w]; nt < tab[w + 1]; ++nt) {
        f32x4 acc = {0.f, 0.f, 0.f, 0.f};
        const u16* bbase = g_f2w + (size_t)(nt * 16 + l15) * HSTR + quad * 8;
        #pragma unroll
        for (int ks = 0; ks < 3; ++ks) {
            bf16x8 bfr = *(const bf16x8*)(bbase + ks * 32);
            acc = __builtin_amdgcn_mfma_f32_16x16x32_bf16(areg[ks], bfr, acc, 0, 0, 0);
        }
        int o = nt * 16 + l15;
        float bias = ldin(fc2_b, o, bf);
        #pragma unroll
        for (int r = 0; r < 4; ++r) {
            size_t token = tok0 + quad * 4 + r;
            t2f[quad * 4 + r][o] = bits2f(g_t1[token * D + o]) + acc[r] + bias;
        }
    }
    __syncthreads();
    int b_ = (int)(tok0 >> 12), n0 = (int)(tok0 & 4095);
    for (int idx = tid; idx < D * 16; idx += 256) {
        int o = idx >> 4, t = idx & 15;
        g_t2[((size_t)b_ * D + o) * NN + n0 + t] = t2f[t][o];
    }
}

// ---- fold -> out (coalesced reads from transposed t2)
__global__ void k_fold(void* __restrict__ out) {
    int bf = g_flag;
    int idx = blockIdx.x * blockDim.x + threadIdx.x;
    if (idx >= BB * CCH * HH * WW) return;
    int xx = idx % WW;
    int y = (idx / WW) % HH;
    int c = (idx / (WW * HH)) % CCH;
    int b = idx / (WW * HH * CCH);
    const float* base = g_t2 + ((size_t)b * D + c * 9) * NN;
    float s = 0.f;
    #pragma unroll
    for (int i = 0; i < 3; ++i) {
        int sy = y + 1 - i;
        if (sy < 0 || sy >= HH) continue;
        #pragma unroll
        for (int j = 0; j < 3; ++j) {
            int sx = xx + 1 - j;
            if (sx < 0 || sx >= WW) continue;
            s += base[(size_t)(i * 3 + j) * NN + sy * WW + sx];
        }
    }
    if (bf) ((bf16*)out)[idx] = __float2bfloat16(s);
    else    ((float*)out)[idx] = s;
}

extern "C" void kernel_launch(void* const* d_in, const int* in_sizes, int n_in,
                              void* d_out, int out_size, void* d_ws, size_t ws_size,
                              hipStream_t stream) {
    const void* x        = d_in[0];
    const void* ln1_w    = d_in[1];
    const void* ln1_b    = d_in[2];
    const void* reduce_w = d_in[3];
    const void* qkv_w    = d_in[4];
    const void* proj_w   = d_in[5];
    const void* proj_b   = d_in[6];
    const void* ln2_w    = d_in[7];
    const void* ln2_b    = d_in[8];
    const void* fc1_w    = d_in[9];
    const void* fc1_b    = d_in[10];
    const void* fc2_w    = d_in[11];
    const void* fc2_b    = d_in[12];

    k_prep        <<<DQ + RSB + PATCHB, 256, 0, stream>>>(x, qkv_w, reduce_w, proj_w, fc1_w, fc2_w);
    k_ln_qkv      <<<BB * NN / 16, 256, 0, stream>>>(ln1_w, ln1_b);
    k_attn        <<<2 * BB * NH * SPLIT * 8, 128, 0, stream>>>();
    k_comb        <<<BB * NH * SPLIT * 4, 256, 0, stream>>>();
    k_proj_ln_fc1 <<<BB * NN / 16, 256, 0, stream>>>(proj_b, ln2_w, ln2_b, fc1_b);
    k_fc2         <<<BB * NN / 16, 256, 0, stream>>>(fc2_b);
    k_fold        <<<(BB * CCH * HH * WW + 255) / 256, 256, 0, stream>>>(d_out);
}

// Round 15
// 220.324 us; speedup vs baseline: 1.0301x; 1.0301x over previous
//
#include <hip/hip_runtime.h>
#include <hip/hip_bf16.h>

typedef __hip_bfloat16 bf16;
typedef unsigned short u16;
typedef unsigned int u32;
typedef __attribute__((ext_vector_type(8))) short bf16x8;
typedef __attribute__((ext_vector_type(4))) float f32x4;

#define BB 4
#define CCH 32
#define HH 64
#define WW 64
#define NN 4096
#define D 288
#define DR 144
#define DQ 432
#define NH 8
#define HD 18
#define SPLIT 4
#define CHUNK 1024
#define KS 512        // keys per split-K slice
#define DH 72
#define SCALE_ 0.16666666666666666f
#define QSCALE 0.24044917348149343f   // SCALE_ * log2(e): softmax via exp2
#define EPS_ 1e-5f
#define ASTR 160      // g_pw row stride (K-padded)
#define ATS 168       // attnT LDS row stride (2-way bank aliasing only)
#define HSTR 96

// ---- static device workspace (.bss zeros; pad regions stay zero except vt row 18 = 1.0)
__device__ __attribute__((aligned(16))) u16 g_Wcb[DQ * D];
__device__ __attribute__((aligned(16))) u16 g_pw[D * ASTR];
__device__ __attribute__((aligned(16))) u16 g_f1w[HSTR * D];
__device__ __attribute__((aligned(16))) u16 g_f2w[D * HSTR];
__device__ __attribute__((aligned(16))) u16 g_q[(size_t)BB * NH * NN * 32];
__device__ __attribute__((aligned(16))) u16 g_k[(size_t)BB * NH * NN * 32];
__device__ __attribute__((aligned(16))) u16 g_vt[(size_t)BB * NH * SPLIT * 32 * CHUNK];
__device__ __attribute__((aligned(16))) float g_part[2 * (size_t)BB * NH * NN * 20]; // split-K partials
__device__ __attribute__((aligned(16))) u16 g_h[(size_t)BB * NN * HSTR];
__device__ __attribute__((aligned(16))) u16 g_t0[(size_t)BB * NN * D];
__device__ __attribute__((aligned(16))) u16 g_t1[(size_t)BB * NN * D];   // bf16 residual stream
__device__ float g_t2[(size_t)BB * D * NN];
__device__ int   g_flag;

__device__ __forceinline__ float b2f(bf16 v) { return __bfloat162float(v); }
__device__ __forceinline__ float bits2f(u16 u) { return __uint_as_float(((u32)u) << 16); }
__device__ __forceinline__ u16 f2bits(float f) {
    u32 u = __float_as_uint(f);
    return (u16)((u + 0x7FFF + ((u >> 16) & 1)) >> 16);   // RNE
}
__device__ __forceinline__ float ldin(const void* p, size_t i, int isbf) {
    return isbf ? b2f(((const bf16*)p)[i]) : ((const float*)p)[i];
}

#define RS  (D * ASTR + HSTR * D + D * HSTR)      // staging elems 101376
#define RS2 (RS + BB * NH * SPLIT * CHUNK)        // + vt ones-row fills = 232448
#define RSB ((RS2 + 255) / 256)                   // 908
#define PATCHB (BB * HH)                          // 256 patch blocks

// ---- prep: dtype detect + Wc GEMM + weight staging + vt ones row + patch extract
__global__ void k_prep(const void* __restrict__ x, const void* __restrict__ qkv_w,
                       const void* __restrict__ reduce_w, const void* __restrict__ proj_w,
                       const void* __restrict__ fc1_w, const void* __restrict__ fc2_w) {
    __shared__ int cnt4[4];
    __shared__ float qw[DR];
    __shared__ float slab[32 * 3 * 66];
    int tid = threadIdx.x;
    {
        const u16* u = (const u16*)x;
        int c = 0;
        for (int i = tid; i < 2048; i += 256) c += (((u[i] >> 7) & 0xFF) >= 0x90);
        for (int o = 32; o; o >>= 1) c += __shfl_xor(c, o);
        if ((tid & 63) == 0) cnt4[tid >> 6] = c;
    }
    __syncthreads();
    int bf = (cnt4[0] + cnt4[1] + cnt4[2] + cnt4[3]) < 32;
    if (tid == 0 && blockIdx.x == 0) g_flag = bf;

    int bid = blockIdx.x;
    if (bid < DQ) {
        int o = bid;
        if (tid < DR) qw[tid] = ldin(qkv_w, (size_t)o * DR + tid, bf);
        __syncthreads();
        for (int col = tid; col < D; col += 256) {
            float s0 = 0.f, s1 = 0.f;
            #pragma unroll 4
            for (int j = 0; j < DR; j += 2) {
                s0 += qw[j] * ldin(reduce_w, (size_t)j * D + col, bf);
                s1 += qw[j + 1] * ldin(reduce_w, (size_t)(j + 1) * D + col, bf);
            }
            g_Wcb[(size_t)o * D + col] = f2bits(s0 + s1);
        }
    } else if (bid < DQ + RSB) {
        int idx = (bid - DQ) * 256 + tid;
        if (idx < D * ASTR) {
            int o = idx / ASTR, j = idx % ASTR;
            g_pw[idx] = (j < DR) ? f2bits(ldin(proj_w, (size_t)o * DR + j, bf)) : (u16)0;
        } else if (idx < D * ASTR + HSTR * D) {
            int t = idx - D * ASTR;
            int o = t / D;
            g_f1w[t] = (o < DH) ? f2bits(ldin(fc1_w, (size_t)t, bf)) : (u16)0;
        } else if (idx < RS) {
            int t = idx - D * ASTR - HSTR * D;
            int o = t / HSTR, j = t % HSTR;
            g_f2w[t] = (j < DH) ? f2bits(ldin(fc2_w, (size_t)o * DH + j, bf)) : (u16)0;
        } else if (idx < RS2) {
            // V^T row 18 := 1.0 -> PV MFMA computes row-sum l at dim 18
            int t = idx - RS;
            int bhs = t >> 10, n = t & 1023;
            g_vt[((size_t)bhs * 32 + 18) * CHUNK + n] = 0x3F80;  // bf16 1.0
        }
    } else {
        // patch extract: block = (b, y)
        int pb = bid - DQ - RSB;
        int b = pb >> 6, y = pb & 63;
        for (int idx = tid; idx < 32 * 3 * 66; idx += 256) {
            int c = idx / 198, rem = idx % 198;
            int ki = rem / 66, col = rem % 66 - 1;
            int sy = y + ki - 1;
            float v = 0.f;
            if (col >= 0 && col < 64 && sy >= 0 && sy < 64)
                v = ldin(x, ((size_t)(b * CCH + c) * HH + sy) * WW + col, bf);
            slab[idx] = v;
        }
        __syncthreads();
        size_t obase = ((size_t)b * NN + y * 64) * D;
        for (int idx = tid; idx < 64 * D; idx += 256) {
            int t = idx / D, f = idx % D;
            int c = f / 9, k = f % 9, ki = k / 3, kj = k % 3;
            g_t0[obase + idx] = f2bits(slab[c * 198 + ki * 66 + t + kj]);
        }
    }
}

// ---- LN1 + qkv GEMM; block = 16 tokens; V staged through LDS (coalesced out)
__global__ void k_ln_qkv(const void* __restrict__ lnw, const void* __restrict__ lnb) {
    __shared__ __attribute__((aligned(16))) u16 xln[16 * 296];
    __shared__ float lnwf[D], lnbf[D];
    __shared__ float smu[16], srs[16];
    __shared__ u16 vbuf[144][18];
    int bf = g_flag;
    int tid = threadIdx.x;
    size_t tok0 = (size_t)blockIdx.x * 16;
    for (int i = tid; i < D; i += 256) { lnwf[i] = ldin(lnw, i, bf); lnbf[i] = ldin(lnb, i, bf); }
    {
        int tt = tid >> 4, p = tid & 15;
        const u32* pr = (const u32*)(g_t0 + (tok0 + tt) * D + p * 18);
        float s = 0.f, q = 0.f;
        #pragma unroll
        for (int j = 0; j < 9; ++j) {
            u32 v = pr[j];
            float a = bits2f((u16)(v & 0xFFFF)), b = bits2f((u16)(v >> 16));
            s += a + b; q += a * a + b * b;
        }
        #pragma unroll
        for (int o = 1; o < 16; o <<= 1) { s += __shfl_xor(s, o); q += __shfl_xor(q, o); }
        if (p == 0) {
            float mu = s / D;
            smu[tt] = mu;
            srs[tt] = rsqrtf(q / D - mu * mu + EPS_);
        }
    }
    __syncthreads();
    for (int idx = tid; idx < 16 * 144; idx += 256) {
        int t = idx / 144, dw = idx % 144;
        u32 v = *(const u32*)(g_t0 + (tok0 + t) * D + 2 * dw);
        float mu = smu[t], rs = srs[t];
        int f = 2 * dw;
        float a = (bits2f((u16)(v & 0xFFFF)) - mu) * rs * lnwf[f] + lnbf[f];
        float b = (bits2f((u16)(v >> 16)) - mu) * rs * lnwf[f + 1] + lnbf[f + 1];
        *(u32*)&xln[t * 296 + f] = (u32)f2bits(a) | ((u32)f2bits(b) << 16);
    }
    __syncthreads();
    int w = tid >> 6, lane = tid & 63, quad = lane >> 4, l15 = lane & 15;
    bf16x8 areg[9];
    const u16* abase = xln + l15 * 296 + quad * 8;
    #pragma unroll
    for (int ks = 0; ks < 9; ++ks) areg[ks] = *(const bf16x8*)(abase + ks * 32);
    int nt0 = w * 7, nt1 = (nt0 + 7 > 27) ? 27 : nt0 + 7;
    for (int nt = nt0; nt < nt1; ++nt) {
        f32x4 acc = {0.f, 0.f, 0.f, 0.f};
        const u16* bbase = g_Wcb + (size_t)(nt * 16 + l15) * D + quad * 8;
        #pragma unroll
        for (int ks = 0; ks < 9; ++ks) {
            bf16x8 bfr = *(const bf16x8*)(bbase + ks * 32);
            acc = __builtin_amdgcn_mfma_f32_16x16x32_bf16(areg[ks], bfr, acc, 0, 0, 0);
        }
        int o = nt * 16 + l15;
        int which = o / DR, rem = o % DR, hh = rem / HD, dd = rem % HD;
        #pragma unroll
        for (int r = 0; r < 4; ++r) {
            size_t token = tok0 + quad * 4 + r;
            int b_ = (int)(token >> 12), n = (int)(token & 4095);
            size_t row = (size_t)(b_ * NH + hh) * NN + n;
            if (which == 0)      g_q[row * 32 + dd] = f2bits(acc[r] * QSCALE);
            else if (which == 1) g_k[row * 32 + dd] = f2bits(acc[r]);
            else                 vbuf[rem][quad * 4 + r] = f2bits(acc[r]);
        }
    }
    __syncthreads();
    {
        int b_ = (int)(tok0 >> 12);
        int n0 = (int)(tok0 & 4095);
        int sIdx = n0 >> 10, nc = n0 & 1023;
        for (int idx = tid; idx < 144 * 16; idx += 256) {
            int rem = idx >> 4, t = idx & 15;
            int hh = rem / HD, dd = rem % HD;
            size_t voff = (((size_t)(b_ * NH + hh) * SPLIT + sIdx) * 32 + dd) * CHUNK + nc + t;
            g_vt[voff] = vbuf[rem][t];
        }
    }
}

// ---- MFMA flash attention, 2-way split-K: 2048 blocks (8/CU), fp32 partials
#define PSTR 72
__global__ __launch_bounds__(128) void k_attn() {
    __shared__ __attribute__((aligned(16))) u16 Pl[2][4][16 * PSTR];  // 18.4 KB
    int bid = blockIdx.x;
    int chunk = bid & 127;              // chunk low -> XCD pinning (both kslices same XCD)
    int qblk = (bid >> 7) & 7;
    int ksl = bid >> 10;                // 0 / 1: key slice
    int s = chunk & 3, bh = chunk >> 2;
    int tid = threadIdx.x;
    int w = tid >> 6, lane = tid & 63, quad = lane >> 4, l15 = lane & 15;

    size_t rowbase = (size_t)bh * NN + s * CHUNK;
    size_t vtbase = ((size_t)bh * SPLIT + s) * 32 * CHUNK;
    const u16* kbase = g_k + rowbase * 32 + quad * 8;
    const u16* vbase = g_vt + vtbase + quad * 8;

    int qbase = qblk * 128 + w * 64;    // token within chunk
    bf16x8 qf[4];
    #pragma unroll
    for (int t = 0; t < 4; ++t)
        qf[t] = *(const bf16x8*)(g_q + (rowbase + qbase + t * 16 + l15) * 32 + quad * 8);

    f32x4 accA[4], accB[4];
    #pragma unroll
    for (int t = 0; t < 4; ++t) {
        accA[t] = (f32x4){0.f, 0.f, 0.f, 0.f};
        accB[t] = (f32x4){0.f, 0.f, 0.f, 0.f};
    }

    int kt0 = ksl * KS;
    for (int kk = 0; kk < KS; kk += 64) {
        int kt = kt0 + kk;
        bf16x8 kf0 = *(const bf16x8*)(kbase + (size_t)(kt + 2 * l15) * 32);
        bf16x8 kf1 = *(const bf16x8*)(kbase + (size_t)(kt + 2 * l15 + 1) * 32);
        bf16x8 kf2 = *(const bf16x8*)(kbase + (size_t)(kt + 32 + 2 * l15) * 32);
        bf16x8 kf3 = *(const bf16x8*)(kbase + (size_t)(kt + 33 + 2 * l15) * 32);
        bf16x8 vA0 = *(const bf16x8*)(vbase + (size_t)l15 * CHUNK + kt);
        bf16x8 vB0 = *(const bf16x8*)(vbase + (size_t)(16 + l15) * CHUNK + kt);
        bf16x8 vA1 = *(const bf16x8*)(vbase + (size_t)l15 * CHUNK + kt + 32);
        bf16x8 vB1 = *(const bf16x8*)(vbase + (size_t)(16 + l15) * CHUNK + kt + 32);
        f32x4 z = {0.f, 0.f, 0.f, 0.f};
        // phase 1: scores + exp2 + perm-packed P stores
        #pragma unroll
        for (int t = 0; t < 4; ++t) {
            u16* pw = Pl[w][t];
            f32x4 S0 = __builtin_amdgcn_mfma_f32_16x16x32_bf16(qf[t], kf0, z, 0, 0, 0);
            f32x4 S1 = __builtin_amdgcn_mfma_f32_16x16x32_bf16(qf[t], kf1, z, 0, 0, 0);
            f32x4 S2 = __builtin_amdgcn_mfma_f32_16x16x32_bf16(qf[t], kf2, z, 0, 0, 0);
            f32x4 S3 = __builtin_amdgcn_mfma_f32_16x16x32_bf16(qf[t], kf3, z, 0, 0, 0);
            #pragma unroll
            for (int r = 0; r < 4; ++r) {
                float p0 = exp2f(S0[r]), p1 = exp2f(S1[r]);
                float p2 = exp2f(S2[r]), p3 = exp2f(S3[r]);
                u32 w0 = __builtin_amdgcn_perm(__float_as_uint(p1), __float_as_uint(p0), 0x07060302u);
                u32 w1 = __builtin_amdgcn_perm(__float_as_uint(p3), __float_as_uint(p2), 0x07060302u);
                *(u32*)&pw[(quad * 4 + r) * PSTR + 2 * l15] = w0;
                *(u32*)&pw[(quad * 4 + r) * PSTR + 32 + 2 * l15] = w1;
            }
        }
        // phase 2: PV (V frags reused 4x); dim 18 of accB accumulates row-sum l
        #pragma unroll
        for (int t = 0; t < 4; ++t) {
            const u16* pw = Pl[w][t];
            bf16x8 pf0 = *(const bf16x8*)&pw[l15 * PSTR + quad * 8];
            bf16x8 pf1 = *(const bf16x8*)&pw[l15 * PSTR + 32 + quad * 8];
            accA[t] = __builtin_amdgcn_mfma_f32_16x16x32_bf16(pf0, vA0, accA[t], 0, 0, 0);
            accB[t] = __builtin_amdgcn_mfma_f32_16x16x32_bf16(pf0, vB0, accB[t], 0, 0, 0);
            accA[t] = __builtin_amdgcn_mfma_f32_16x16x32_bf16(pf1, vA1, accA[t], 0, 0, 0);
            accB[t] = __builtin_amdgcn_mfma_f32_16x16x32_bf16(pf1, vB1, accB[t], 0, 0, 0);
        }
    }
    // write fp32 partials: [ksl][bh][s][tokenc][20]
    float* pb = g_part + (((size_t)ksl * 32 + bh) * SPLIT + s) * (size_t)(CHUNK * 20);
    #pragma unroll
    for (int t = 0; t < 4; ++t) {
        #pragma unroll
        for (int r = 0; r < 4; ++r) {
            int tokenc = qbase + t * 16 + quad * 4 + r;
            float* row = pb + (size_t)tokenc * 20;
            row[l15] = accA[t][r];                     // dims 0-15
            if (l15 < 3) row[16 + l15] = accB[t][r];   // dims 16,17 + l at slot 18
        }
    }
}

// ---- fused split-K combine + proj + residual + LN2 + fc1 + relu; block = 16 tokens
__global__ void k_proj_ln_fc1(const void* __restrict__ proj_b, const void* __restrict__ lnw,
                              const void* __restrict__ lnb, const void* __restrict__ fc1_b) {
    __shared__ float t1f[16][290];
    __shared__ __attribute__((aligned(16))) u16 xln[16 * 296];
    __shared__ __attribute__((aligned(16))) u16 attnT[16 * ATS];
    __shared__ float linv[16][8];
    __shared__ float lnwf[D], lnbf[D];
    __shared__ float smu[16], srs[16];
    int bf = g_flag;
    int tid = threadIdx.x;
    size_t tok0 = (size_t)blockIdx.x * 16;
    int w = tid >> 6, lane = tid & 63, quad = lane >> 4, l15 = lane & 15;
    for (int i = tid; i < D; i += 256) { lnwf[i] = ldin(lnw, i, bf); lnbf[i] = ldin(lnb, i, bf); }

    // phase 0: split-K combine -> attnT (bf16, row stride ATS=168)
    int b_ = (int)(tok0 >> 12);
    int s_ = ((int)tok0 & 4095) >> 10;
    int tc0 = (int)tok0 & 1023;
    if (tid < 128) {
        int t = tid >> 3, h = tid & 7;
        const float* p1 = g_part + (((size_t)(b_ * NH + h)) * SPLIT + s_) * (size_t)(CHUNK * 20)
                        + (size_t)(tc0 + t) * 20;
        const float* p2 = p1 + (size_t)32 * SPLIT * CHUNK * 20;
        linv[t][h] = 1.f / (p1[18] + p2[18]);
    }
    __syncthreads();
    for (int idx = tid; idx < 16 * ATS; idx += 256) {
        int t = idx / ATS, f = idx - t * ATS;
        u16 v = 0;
        if (f < DR) {
            int h = f / HD, d = f - h * HD;
            const float* p1 = g_part + (((size_t)(b_ * NH + h)) * SPLIT + s_) * (size_t)(CHUNK * 20)
                            + (size_t)(tc0 + t) * 20;
            const float* p2 = p1 + (size_t)32 * SPLIT * CHUNK * 20;
            v = f2bits((p1[d] + p2[d]) * linv[t][h]);
        }
        attnT[idx] = v;
    }
    __syncthreads();

    // phase A: proj + residual -> g_t1 and LDS t1f (A-frags from attnT)
    {
        bf16x8 areg[5];
        const u16* abase = attnT + l15 * ATS + quad * 8;
        #pragma unroll
        for (int ks = 0; ks < 5; ++ks) areg[ks] = *(const bf16x8*)(abase + ks * 32);
        const int tab[5] = {0, 5, 10, 14, 18};
        for (int nt = tab[w]; nt < tab[w + 1]; ++nt) {
            f32x4 acc = {0.f, 0.f, 0.f, 0.f};
            const u16* bbase = g_pw + (size_t)(nt * 16 + l15) * ASTR + quad * 8;
            #pragma unroll
            for (int ks = 0; ks < 5; ++ks) {
                bf16x8 bfr = *(const bf16x8*)(bbase + ks * 32);
                acc = __builtin_amdgcn_mfma_f32_16x16x32_bf16(areg[ks], bfr, acc, 0, 0, 0);
            }
            int o = nt * 16 + l15;
            float bias = ldin(proj_b, o, bf);
            #pragma unroll
            for (int r = 0; r < 4; ++r) {
                size_t token = tok0 + quad * 4 + r;
                size_t off = token * D + o;
                float val = bits2f(g_t0[off]) + acc[r] + bias;
                g_t1[off] = f2bits(val);
                t1f[quad * 4 + r][o] = val;
            }
        }
    }
    __syncthreads();
    {
        int tt = tid >> 4, p = tid & 15;
        const float* src = &t1f[tt][p * 18];
        float s = 0.f, q = 0.f;
        #pragma unroll
        for (int j = 0; j < 18; ++j) { float a = src[j]; s += a; q += a * a; }
        #pragma unroll
        for (int o = 1; o < 16; o <<= 1) { s += __shfl_xor(s, o); q += __shfl_xor(q, o); }
        if (p == 0) {
            float mu = s / D;
            smu[tt] = mu;
            srs[tt] = rsqrtf(q / D - mu * mu + EPS_);
        }
    }
    __syncthreads();
    for (int idx = tid; idx < 16 * 144; idx += 256) {
        int t = idx / 144, dw = idx % 144;
        int f = 2 * dw;
        float mu = smu[t], rs = srs[t];
        float a = (t1f[t][f] - mu) * rs * lnwf[f] + lnbf[f];
        float b = (t1f[t][f + 1] - mu) * rs * lnwf[f + 1] + lnbf[f + 1];
        *(u32*)&xln[t * 296 + f] = (u32)f2bits(a) | ((u32)f2bits(b) << 16);
    }
    __syncthreads();
    {
        bf16x8 areg[9];
        const u16* abase = xln + l15 * 296 + quad * 8;
        #pragma unroll
        for (int ks = 0; ks < 9; ++ks) areg[ks] = *(const bf16x8*)(abase + ks * 32);
        const int tab2[5] = {0, 2, 4, 5, 6};
        for (int nt = tab2[w]; nt < tab2[w + 1]; ++nt) {
            f32x4 acc = {0.f, 0.f, 0.f, 0.f};
            const u16* bbase = g_f1w + (size_t)(nt * 16 + l15) * D + quad * 8;
            #pragma unroll
            for (int ks = 0; ks < 9; ++ks) {
                bf16x8 bfr = *(const bf16x8*)(bbase + ks * 32);
                acc = __builtin_amdgcn_mfma_f32_16x16x32_bf16(areg[ks], bfr, acc, 0, 0, 0);
            }
            int o = nt * 16 + l15;
            float bias = (o < DH) ? ldin(fc1_b, o, bf) : 0.f;
            #pragma unroll
            for (int r = 0; r < 4; ++r) {
                size_t token = tok0 + quad * 4 + r;
                g_h[token * HSTR + o] = f2bits(fmaxf(acc[r] + bias, 0.f));
            }
        }
    }
}

// ---- fc2 + residual -> g_t2 transposed via LDS (64B-segment stores)
__global__ void k_fc2(const void* __restrict__ fc2_b) {
    __shared__ float t2f[16][293];   // stride 293: conflict-free transpose read
    int bf = g_flag;
    int tid = threadIdx.x;
    size_t tok0 = (size_t)blockIdx.x * 16;
    int w = tid >> 6, lane = tid & 63, quad = lane >> 4, l15 = lane & 15;
    bf16x8 areg[3];
    const u16* abase = g_h + (tok0 + l15) * HSTR + quad * 8;
    #pragma unroll
    for (int ks = 0; ks < 3; ++ks) areg[ks] = *(const bf16x8*)(abase + ks * 32);
    const int tab[5] = {0, 5, 10, 14, 18};
    for (int nt = tab[w]; nt < tab[w + 1]; ++nt) {
        f32x4 acc = {0.f, 0.f, 0.f, 0.f};
        const u16* bbase = g_f2w + (size_t)(nt * 16 + l15) * HSTR + quad * 8;
        #pragma unroll
        for (int ks = 0; ks < 3; ++ks) {
            bf16x8 bfr = *(const bf16x8*)(bbase + ks * 32);
            acc = __builtin_amdgcn_mfma_f32_16x16x32_bf16(areg[ks], bfr, acc, 0, 0, 0);
        }
        int o = nt * 16 + l15;
        float bias = ldin(fc2_b, o, bf);
        #pragma unroll
        for (int r = 0; r < 4; ++r) {
            size_t token = tok0 + quad * 4 + r;
            t2f[quad * 4 + r][o] = bits2f(g_t1[token * D + o]) + acc[r] + bias;
        }
    }
    __syncthreads();
    int b_ = (int)(tok0 >> 12), n0 = (int)(tok0 & 4095);
    for (int idx = tid; idx < D * 16; idx += 256) {
        int o = idx >> 4, t = idx & 15;
        g_t2[((size_t)b_ * D + o) * NN + n0 + t] = t2f[t][o];
    }
}

// ---- fold -> out (coalesced reads from transposed t2)
__global__ void k_fold(void* __restrict__ out) {
    int bf = g_flag;
    int idx = blockIdx.x * blockDim.x + threadIdx.x;
    if (idx >= BB * CCH * HH * WW) return;
    int xx = idx % WW;
    int y = (idx / WW) % HH;
    int c = (idx / (WW * HH)) % CCH;
    int b = idx / (WW * HH * CCH);
    const float* base = g_t2 + ((size_t)b * D + c * 9) * NN;
    float s = 0.f;
    #pragma unroll
    for (int i = 0; i < 3; ++i) {
        int sy = y + 1 - i;
        if (sy < 0 || sy >= HH) continue;
        #pragma unroll
        for (int j = 0; j < 3; ++j) {
            int sx = xx + 1 - j;
            if (sx < 0 || sx >= WW) continue;
            s += base[(size_t)(i * 3 + j) * NN + sy * WW + sx];
        }
    }
    if (bf) ((bf16*)out)[idx] = __float2bfloat16(s);
    else    ((float*)out)[idx] = s;
}

extern "C" void kernel_launch(void* const* d_in, const int* in_sizes, int n_in,
                              void* d_out, int out_size, void* d_ws, size_t ws_size,
                              hipStream_t stream) {
    const void* x        = d_in[0];
    const void* ln1_w    = d_in[1];
    const void* ln1_b    = d_in[2];
    const void* reduce_w = d_in[3];
    const void* qkv_w    = d_in[4];
    const void* proj_w   = d_in[5];
    const void* proj_b   = d_in[6];
    const void* ln2_w    = d_in[7];
    const void* ln2_b    = d_in[8];
    const void* fc1_w    = d_in[9];
    const void* fc1_b    = d_in[10];
    const void* fc2_w    = d_in[11];
    const void* fc2_b    = d_in[12];

    k_prep        <<<DQ + RSB + PATCHB, 256, 0, stream>>>(x, qkv_w, reduce_w, proj_w, fc1_w, fc2_w);
    k_ln_qkv      <<<BB * NN / 16, 256, 0, stream>>>(ln1_w, ln1_b);
    k_attn        <<<2 * BB * NH * SPLIT * 8, 128, 0, stream>>>();
    k_proj_ln_fc1 <<<BB * NN / 16, 256, 0, stream>>>(proj_b, ln2_w, ln2_b, fc1_b);
    k_fc2         <<<BB * NN / 16, 256, 0, stream>>>(fc2_b);
    k_fold        <<<(BB * CCH * HH * WW + 255) / 256, 256, 0, stream>>>(d_out);
}

// Round 16
// 218.161 us; speedup vs baseline: 1.0404x; 1.0099x over previous
//
#include <hip/hip_runtime.h>
#include <hip/hip_bf16.h>

typedef __hip_bfloat16 bf16;
typedef unsigned short u16;
typedef unsigned int u32;
typedef __attribute__((ext_vector_type(8))) short bf16x8;
typedef __attribute__((ext_vector_type(4))) float f32x4;

#define BB 4
#define CCH 32
#define HH 64
#define WW 64
#define NN 4096
#define D 288
#define DR 144
#define DQ 432
#define NH 8
#define HD 18
#define SPLIT 4
#define CHUNK 1024
#define KS 512        // keys per split-K slice
#define DH 72
#define SCALE_ 0.16666666666666666f
#define QSCALE 0.24044917348149343f   // SCALE_ * log2(e): softmax via exp2
#define EPS_ 1e-5f
#define ASTR 160      // g_pw row stride (K-padded)
#define ATS 168       // attnT LDS row stride
#define HSTR 96

// ---- static device workspace (.bss zeros; pad regions stay zero except vt row 18 = 1.0)
__device__ __attribute__((aligned(16))) u16 g_Wcb[DQ * D];
__device__ __attribute__((aligned(16))) u16 g_pw[D * ASTR];
__device__ __attribute__((aligned(16))) u16 g_f1w[HSTR * D];
__device__ __attribute__((aligned(16))) u16 g_f2w[D * HSTR];
__device__ __attribute__((aligned(16))) u16 g_q[(size_t)BB * NH * NN * 32];
__device__ __attribute__((aligned(16))) u16 g_k[(size_t)BB * NH * NN * 32];
__device__ __attribute__((aligned(16))) u16 g_vt[(size_t)BB * NH * SPLIT * 32 * CHUNK];
__device__ __attribute__((aligned(16))) float g_part[2 * (size_t)BB * NH * NN * 20]; // split-K partials
__device__ __attribute__((aligned(16))) u16 g_h[(size_t)BB * NN * HSTR];
__device__ __attribute__((aligned(16))) u16 g_t0[(size_t)BB * NN * D];
__device__ __attribute__((aligned(16))) u16 g_t1[(size_t)BB * NN * D];   // bf16 residual stream
__device__ __attribute__((aligned(16))) u16 g_t2b[(size_t)BB * D * NN];  // bf16 transposed t2
__device__ int   g_flag;

__device__ __forceinline__ float b2f(bf16 v) { return __bfloat162float(v); }
__device__ __forceinline__ float bits2f(u16 u) { return __uint_as_float(((u32)u) << 16); }
__device__ __forceinline__ u16 f2bits(float f) {
    u32 u = __float_as_uint(f);
    return (u16)((u + 0x7FFF + ((u >> 16) & 1)) >> 16);   // RNE
}
__device__ __forceinline__ float ldin(const void* p, size_t i, int isbf) {
    return isbf ? b2f(((const bf16*)p)[i]) : ((const float*)p)[i];
}

#define RS  (D * ASTR + HSTR * D + D * HSTR)      // staging elems 101376
#define RS2 (RS + BB * NH * SPLIT * CHUNK)        // + vt ones-row fills = 232448
#define RSB ((RS2 + 255) / 256)                   // 908
#define PATCHB (BB * HH)                          // 256 patch blocks

// ---- prep: dtype detect + Wc GEMM + weight staging + vt ones row + patch extract
__global__ void k_prep(const void* __restrict__ x, const void* __restrict__ qkv_w,
                       const void* __restrict__ reduce_w, const void* __restrict__ proj_w,
                       const void* __restrict__ fc1_w, const void* __restrict__ fc2_w) {
    __shared__ int cnt4[4];
    __shared__ float qw[DR];
    __shared__ float slab[32 * 3 * 66];
    int tid = threadIdx.x;
    {
        const u16* u = (const u16*)x;
        int c = 0;
        for (int i = tid; i < 2048; i += 256) c += (((u[i] >> 7) & 0xFF) >= 0x90);
        for (int o = 32; o; o >>= 1) c += __shfl_xor(c, o);
        if ((tid & 63) == 0) cnt4[tid >> 6] = c;
    }
    __syncthreads();
    int bf = (cnt4[0] + cnt4[1] + cnt4[2] + cnt4[3]) < 32;
    if (tid == 0 && blockIdx.x == 0) g_flag = bf;

    int bid = blockIdx.x;
    if (bid < DQ) {
        int o = bid;
        if (tid < DR) qw[tid] = ldin(qkv_w, (size_t)o * DR + tid, bf);
        __syncthreads();
        for (int col = tid; col < D; col += 256) {
            float s0 = 0.f, s1 = 0.f;
            #pragma unroll 4
            for (int j = 0; j < DR; j += 2) {
                s0 += qw[j] * ldin(reduce_w, (size_t)j * D + col, bf);
                s1 += qw[j + 1] * ldin(reduce_w, (size_t)(j + 1) * D + col, bf);
            }
            g_Wcb[(size_t)o * D + col] = f2bits(s0 + s1);
        }
    } else if (bid < DQ + RSB) {
        int idx = (bid - DQ) * 256 + tid;
        if (idx < D * ASTR) {
            int o = idx / ASTR, j = idx % ASTR;
            g_pw[idx] = (j < DR) ? f2bits(ldin(proj_w, (size_t)o * DR + j, bf)) : (u16)0;
        } else if (idx < D * ASTR + HSTR * D) {
            int t = idx - D * ASTR;
            int o = t / D;
            g_f1w[t] = (o < DH) ? f2bits(ldin(fc1_w, (size_t)t, bf)) : (u16)0;
        } else if (idx < RS) {
            int t = idx - D * ASTR - HSTR * D;
            int o = t / HSTR, j = t % HSTR;
            g_f2w[t] = (j < DH) ? f2bits(ldin(fc2_w, (size_t)o * DH + j, bf)) : (u16)0;
        } else if (idx < RS2) {
            // V^T row 18 := 1.0 -> PV MFMA computes row-sum l at dim 18
            int t = idx - RS;
            int bhs = t >> 10, n = t & 1023;
            g_vt[((size_t)bhs * 32 + 18) * CHUNK + n] = 0x3F80;  // bf16 1.0
        }
    } else {
        // patch extract: block = (b, y)
        int pb = bid - DQ - RSB;
        int b = pb >> 6, y = pb & 63;
        for (int idx = tid; idx < 32 * 3 * 66; idx += 256) {
            int c = idx / 198, rem = idx % 198;
            int ki = rem / 66, col = rem % 66 - 1;
            int sy = y + ki - 1;
            float v = 0.f;
            if (col >= 0 && col < 64 && sy >= 0 && sy < 64)
                v = ldin(x, ((size_t)(b * CCH + c) * HH + sy) * WW + col, bf);
            slab[idx] = v;
        }
        __syncthreads();
        size_t obase = ((size_t)b * NN + y * 64) * D;
        for (int idx = tid; idx < 64 * D; idx += 256) {
            int t = idx / D, f = idx % D;
            int c = f / 9, k = f % 9, ki = k / 3, kj = k % 3;
            g_t0[obase + idx] = f2bits(slab[c * 198 + ki * 66 + t + kj]);
        }
    }
}

// ---- LN1 + qkv GEMM; block = 16 tokens; q/k/v all staged through LDS, coalesced u32 out
__global__ void k_ln_qkv(const void* __restrict__ lnw, const void* __restrict__ lnb) {
    __shared__ __attribute__((aligned(16))) u16 xln[16 * 296];
    __shared__ float lnwf[D], lnbf[D];
    __shared__ float smu[16], srs[16];
    __shared__ u16 buf[3][144][16];   // [q/k/v][h*18+dd][token]
    int bf = g_flag;
    int tid = threadIdx.x;
    size_t tok0 = (size_t)blockIdx.x * 16;
    for (int i = tid; i < D; i += 256) { lnwf[i] = ldin(lnw, i, bf); lnbf[i] = ldin(lnb, i, bf); }
    {
        int tt = tid >> 4, p = tid & 15;
        const u32* pr = (const u32*)(g_t0 + (tok0 + tt) * D + p * 18);
        float s = 0.f, q = 0.f;
        #pragma unroll
        for (int j = 0; j < 9; ++j) {
            u32 v = pr[j];
            float a = bits2f((u16)(v & 0xFFFF)), b = bits2f((u16)(v >> 16));
            s += a + b; q += a * a + b * b;
        }
        #pragma unroll
        for (int o = 1; o < 16; o <<= 1) { s += __shfl_xor(s, o); q += __shfl_xor(q, o); }
        if (p == 0) {
            float mu = s / D;
            smu[tt] = mu;
            srs[tt] = rsqrtf(q / D - mu * mu + EPS_);
        }
    }
    __syncthreads();
    for (int idx = tid; idx < 16 * 144; idx += 256) {
        int t = idx / 144, dw = idx % 144;
        u32 v = *(const u32*)(g_t0 + (tok0 + t) * D + 2 * dw);
        float mu = smu[t], rs = srs[t];
        int f = 2 * dw;
        float a = (bits2f((u16)(v & 0xFFFF)) - mu) * rs * lnwf[f] + lnbf[f];
        float b = (bits2f((u16)(v >> 16)) - mu) * rs * lnwf[f + 1] + lnbf[f + 1];
        *(u32*)&xln[t * 296 + f] = (u32)f2bits(a) | ((u32)f2bits(b) << 16);
    }
    __syncthreads();
    int w = tid >> 6, lane = tid & 63, quad = lane >> 4, l15 = lane & 15;
    bf16x8 areg[9];
    const u16* abase = xln + l15 * 296 + quad * 8;
    #pragma unroll
    for (int ks = 0; ks < 9; ++ks) areg[ks] = *(const bf16x8*)(abase + ks * 32);
    int nt0 = w * 7, nt1 = (nt0 + 7 > 27) ? 27 : nt0 + 7;
    for (int nt = nt0; nt < nt1; ++nt) {
        f32x4 acc = {0.f, 0.f, 0.f, 0.f};
        const u16* bbase = g_Wcb + (size_t)(nt * 16 + l15) * D + quad * 8;
        #pragma unroll
        for (int ks = 0; ks < 9; ++ks) {
            bf16x8 bfr = *(const bf16x8*)(bbase + ks * 32);
            acc = __builtin_amdgcn_mfma_f32_16x16x32_bf16(areg[ks], bfr, acc, 0, 0, 0);
        }
        int o = nt * 16 + l15;
        int which = o / DR, rem = o % DR;
        #pragma unroll
        for (int r = 0; r < 4; ++r)
            buf[which][rem][quad * 4 + r] = f2bits(which == 0 ? acc[r] * QSCALE : acc[r]);
    }
    __syncthreads();
    {
        int b_ = (int)(tok0 >> 12);
        int n0 = (int)(tok0 & 4095);
        int sIdx = n0 >> 10, nc = n0 & 1023;
        // q & k: [row][32] layout, u32-packed (dims 2dw,2dw+1), coalesced per head
        for (int idx = tid; idx < 2 * 8 * 16 * 9; idx += 256) {
            int which = idx / 1152;
            int r2 = idx - which * 1152;
            int h = r2 / 144, r3 = r2 % 144, t = r3 / 9, dw = r3 % 9;
            u32 lo = buf[which][h * 18 + 2 * dw][t];
            u32 hi = buf[which][h * 18 + 2 * dw + 1][t];
            u16* dst = (which ? g_k : g_q) + ((size_t)(b_ * NH + h) * NN + n0 + t) * 32 + 2 * dw;
            *(u32*)dst = lo | (hi << 16);
        }
        // v: [dd][CHUNK] layout, u32-packed token pairs
        for (int idx = tid; idx < 144 * 8; idx += 256) {
            int rem = idx >> 3, tp = idx & 7;
            int hh = rem / HD, dd = rem % HD;
            u32 lo = buf[2][rem][2 * tp];
            u32 hi = buf[2][rem][2 * tp + 1];
            size_t voff = (((size_t)(b_ * NH + hh) * SPLIT + sIdx) * 32 + dd) * CHUNK + nc + 2 * tp;
            *(u32*)&g_vt[voff] = lo | (hi << 16);
        }
    }
}

// ---- MFMA flash attention, 2-way split-K: 2048 blocks (8/CU), fp32 partials
#define PSTR 72
__global__ __launch_bounds__(128) void k_attn() {
    __shared__ __attribute__((aligned(16))) u16 Pl[2][4][16 * PSTR];  // 18.4 KB
    int bid = blockIdx.x;
    int chunk = bid & 127;              // chunk low -> XCD pinning (both kslices same XCD)
    int qblk = (bid >> 7) & 7;
    int ksl = bid >> 10;                // 0 / 1: key slice
    int s = chunk & 3, bh = chunk >> 2;
    int tid = threadIdx.x;
    int w = tid >> 6, lane = tid & 63, quad = lane >> 4, l15 = lane & 15;

    size_t rowbase = (size_t)bh * NN + s * CHUNK;
    size_t vtbase = ((size_t)bh * SPLIT + s) * 32 * CHUNK;
    const u16* kbase = g_k + rowbase * 32 + quad * 8;
    const u16* vbase = g_vt + vtbase + quad * 8;

    int qbase = qblk * 128 + w * 64;    // token within chunk
    bf16x8 qf[4];
    #pragma unroll
    for (int t = 0; t < 4; ++t)
        qf[t] = *(const bf16x8*)(g_q + (rowbase + qbase + t * 16 + l15) * 32 + quad * 8);

    f32x4 accA[4], accB[4];
    #pragma unroll
    for (int t = 0; t < 4; ++t) {
        accA[t] = (f32x4){0.f, 0.f, 0.f, 0.f};
        accB[t] = (f32x4){0.f, 0.f, 0.f, 0.f};
    }

    int kt0 = ksl * KS;
    for (int kk = 0; kk < KS; kk += 64) {
        int kt = kt0 + kk;
        bf16x8 kf0 = *(const bf16x8*)(kbase + (size_t)(kt + 2 * l15) * 32);
        bf16x8 kf1 = *(const bf16x8*)(kbase + (size_t)(kt + 2 * l15 + 1) * 32);
        bf16x8 kf2 = *(const bf16x8*)(kbase + (size_t)(kt + 32 + 2 * l15) * 32);
        bf16x8 kf3 = *(const bf16x8*)(kbase + (size_t)(kt + 33 + 2 * l15) * 32);
        bf16x8 vA0 = *(const bf16x8*)(vbase + (size_t)l15 * CHUNK + kt);
        bf16x8 vB0 = *(const bf16x8*)(vbase + (size_t)(16 + l15) * CHUNK + kt);
        bf16x8 vA1 = *(const bf16x8*)(vbase + (size_t)l15 * CHUNK + kt + 32);
        bf16x8 vB1 = *(const bf16x8*)(vbase + (size_t)(16 + l15) * CHUNK + kt + 32);
        f32x4 z = {0.f, 0.f, 0.f, 0.f};
        // phase 1: scores + exp2 + perm-packed P stores
        #pragma unroll
        for (int t = 0; t < 4; ++t) {
            u16* pw = Pl[w][t];
            f32x4 S0 = __builtin_amdgcn_mfma_f32_16x16x32_bf16(qf[t], kf0, z, 0, 0, 0);
            f32x4 S1 = __builtin_amdgcn_mfma_f32_16x16x32_bf16(qf[t], kf1, z, 0, 0, 0);
            f32x4 S2 = __builtin_amdgcn_mfma_f32_16x16x32_bf16(qf[t], kf2, z, 0, 0, 0);
            f32x4 S3 = __builtin_amdgcn_mfma_f32_16x16x32_bf16(qf[t], kf3, z, 0, 0, 0);
            #pragma unroll
            for (int r = 0; r < 4; ++r) {
                float p0 = exp2f(S0[r]), p1 = exp2f(S1[r]);
                float p2 = exp2f(S2[r]), p3 = exp2f(S3[r]);
                u32 w0 = __builtin_amdgcn_perm(__float_as_uint(p1), __float_as_uint(p0), 0x07060302u);
                u32 w1 = __builtin_amdgcn_perm(__float_as_uint(p3), __float_as_uint(p2), 0x07060302u);
                *(u32*)&pw[(quad * 4 + r) * PSTR + 2 * l15] = w0;
                *(u32*)&pw[(quad * 4 + r) * PSTR + 32 + 2 * l15] = w1;
            }
        }
        // phase 2: PV (V frags reused 4x); dim 18 of accB accumulates row-sum l
        #pragma unroll
        for (int t = 0; t < 4; ++t) {
            const u16* pw = Pl[w][t];
            bf16x8 pf0 = *(const bf16x8*)&pw[l15 * PSTR + quad * 8];
            bf16x8 pf1 = *(const bf16x8*)&pw[l15 * PSTR + 32 + quad * 8];
            accA[t] = __builtin_amdgcn_mfma_f32_16x16x32_bf16(pf0, vA0, accA[t], 0, 0, 0);
            accB[t] = __builtin_amdgcn_mfma_f32_16x16x32_bf16(pf0, vB0, accB[t], 0, 0, 0);
            accA[t] = __builtin_amdgcn_mfma_f32_16x16x32_bf16(pf1, vA1, accA[t], 0, 0, 0);
            accB[t] = __builtin_amdgcn_mfma_f32_16x16x32_bf16(pf1, vB1, accB[t], 0, 0, 0);
        }
    }
    // write fp32 partials: [ksl][bh][s][tokenc][20]
    float* pb = g_part + (((size_t)ksl * 32 + bh) * SPLIT + s) * (size_t)(CHUNK * 20);
    #pragma unroll
    for (int t = 0; t < 4; ++t) {
        #pragma unroll
        for (int r = 0; r < 4; ++r) {
            int tokenc = qbase + t * 16 + quad * 4 + r;
            float* row = pb + (size_t)tokenc * 20;
            row[l15] = accA[t][r];                     // dims 0-15
            if (l15 < 3) row[16 + l15] = accB[t][r];   // dims 16,17 + l at slot 18
        }
    }
}

// ---- fused split-K combine + proj + residual + LN2 + fc1 + relu; block = 16 tokens
__global__ void k_proj_ln_fc1(const void* __restrict__ proj_b, const void* __restrict__ lnw,
                              const void* __restrict__ lnb, const void* __restrict__ fc1_b) {
    __shared__ float t1f[16][290];
    __shared__ __attribute__((aligned(16))) u16 xln[16 * 296];
    __shared__ __attribute__((aligned(16))) u16 attnT[16 * ATS];
    __shared__ float lnwf[D], lnbf[D];
    __shared__ float smu[16], srs[16];
    int bf = g_flag;
    int tid = threadIdx.x;
    size_t tok0 = (size_t)blockIdx.x * 16;
    int w = tid >> 6, lane = tid & 63, quad = lane >> 4, l15 = lane & 15;
    for (int i = tid; i < D; i += 256) { lnwf[i] = ldin(lnw, i, bf); lnbf[i] = ldin(lnb, i, bf); }

    // phase 0: vectorized split-K combine -> attnT (bf16, row stride ATS)
    int b_ = (int)(tok0 >> 12);
    int s_ = ((int)tok0 & 4095) >> 10;
    int tc0 = (int)tok0 & 1023;
    for (int idx = tid; idx < 16 * (ATS - DR); idx += 256) {   // zero pads 144..167
        int t = idx / (ATS - DR), f = idx % (ATS - DR);
        attnT[t * ATS + DR + f] = 0;
    }
    if (tid < 128) {
        int t = tid >> 3, h = tid & 7;
        const float* p1 = g_part + (((size_t)(b_ * NH + h)) * SPLIT + s_) * (size_t)(CHUNK * 20)
                        + (size_t)(tc0 + t) * 20;
        const float* p2 = p1 + (size_t)32 * SPLIT * CHUNK * 20;
        f32x4 a0 = *(const f32x4*)p1,        c0 = *(const f32x4*)p2;
        f32x4 a1 = *(const f32x4*)(p1 + 4),  c1 = *(const f32x4*)(p2 + 4);
        f32x4 a2 = *(const f32x4*)(p1 + 8),  c2 = *(const f32x4*)(p2 + 8);
        f32x4 a3 = *(const f32x4*)(p1 + 12), c3 = *(const f32x4*)(p2 + 12);
        f32x4 a4 = *(const f32x4*)(p1 + 16), c4 = *(const f32x4*)(p2 + 16);
        float inv = 1.f / (a4[2] + c4[2]);
        u16* dst = attnT + t * ATS + h * HD;
        #pragma unroll
        for (int d = 0; d < 4; ++d) {
            dst[d]      = f2bits((a0[d] + c0[d]) * inv);
            dst[4 + d]  = f2bits((a1[d] + c1[d]) * inv);
            dst[8 + d]  = f2bits((a2[d] + c2[d]) * inv);
            dst[12 + d] = f2bits((a3[d] + c3[d]) * inv);
        }
        dst[16] = f2bits((a4[0] + c4[0]) * inv);
        dst[17] = f2bits((a4[1] + c4[1]) * inv);
    }
    __syncthreads();

    // phase A: proj + residual -> g_t1 and LDS t1f (A-frags from attnT)
    {
        bf16x8 areg[5];
        const u16* abase = attnT + l15 * ATS + quad * 8;
        #pragma unroll
        for (int ks = 0; ks < 5; ++ks) areg[ks] = *(const bf16x8*)(abase + ks * 32);
        const int tab[5] = {0, 5, 10, 14, 18};
        for (int nt = tab[w]; nt < tab[w + 1]; ++nt) {
            f32x4 acc = {0.f, 0.f, 0.f, 0.f};
            const u16* bbase = g_pw + (size_t)(nt * 16 + l15) * ASTR + quad * 8;
            #pragma unroll
            for (int ks = 0; ks < 5; ++ks) {
                bf16x8 bfr = *(const bf16x8*)(bbase + ks * 32);
                acc = __builtin_amdgcn_mfma_f32_16x16x32_bf16(areg[ks], bfr, acc, 0, 0, 0);
            }
            int o = nt * 16 + l15;
            float bias = ldin(proj_b, o, bf);
            #pragma unroll
            for (int r = 0; r < 4; ++r) {
                size_t token = tok0 + quad * 4 + r;
                size_t off = token * D + o;
                float val = bits2f(g_t0[off]) + acc[r] + bias;
                g_t1[off] = f2bits(val);
                t1f[quad * 4 + r][o] = val;
            }
        }
    }
    __syncthreads();
    {
        int tt = tid >> 4, p = tid & 15;
        const float* src = &t1f[tt][p * 18];
        float s = 0.f, q = 0.f;
        #pragma unroll
        for (int j = 0; j < 18; ++j) { float a = src[j]; s += a; q += a * a; }
        #pragma unroll
        for (int o = 1; o < 16; o <<= 1) { s += __shfl_xor(s, o); q += __shfl_xor(q, o); }
        if (p == 0) {
            float mu = s / D;
            smu[tt] = mu;
            srs[tt] = rsqrtf(q / D - mu * mu + EPS_);
        }
    }
    __syncthreads();
    for (int idx = tid; idx < 16 * 144; idx += 256) {
        int t = idx / 144, dw = idx % 144;
        int f = 2 * dw;
        float mu = smu[t], rs = srs[t];
        float a = (t1f[t][f] - mu) * rs * lnwf[f] + lnbf[f];
        float b = (t1f[t][f + 1] - mu) * rs * lnwf[f + 1] + lnbf[f + 1];
        *(u32*)&xln[t * 296 + f] = (u32)f2bits(a) | ((u32)f2bits(b) << 16);
    }
    __syncthreads();
    {
        bf16x8 areg[9];
        const u16* abase = xln + l15 * 296 + quad * 8;
        #pragma unroll
        for (int ks = 0; ks < 9; ++ks) areg[ks] = *(const bf16x8*)(abase + ks * 32);
        const int tab2[5] = {0, 2, 4, 5, 6};
        for (int nt = tab2[w]; nt < tab2[w + 1]; ++nt) {
            f32x4 acc = {0.f, 0.f, 0.f, 0.f};
            const u16* bbase = g_f1w + (size_t)(nt * 16 + l15) * D + quad * 8;
            #pragma unroll
            for (int ks = 0; ks < 9; ++ks) {
                bf16x8 bfr = *(const bf16x8*)(bbase + ks * 32);
                acc = __builtin_amdgcn_mfma_f32_16x16x32_bf16(areg[ks], bfr, acc, 0, 0, 0);
            }
            int o = nt * 16 + l15;
            float bias = (o < DH) ? ldin(fc1_b, o, bf) : 0.f;
            #pragma unroll
            for (int r = 0; r < 4; ++r) {
                size_t token = tok0 + quad * 4 + r;
                g_h[token * HSTR + o] = f2bits(fmaxf(acc[r] + bias, 0.f));
            }
        }
    }
}

// ---- fc2 + residual -> g_t2b (bf16, transposed) via LDS, u32-packed stores
__global__ void k_fc2(const void* __restrict__ fc2_b) {
    __shared__ float t2f[16][293];   // stride 293: conflict-free transpose read
    int bf = g_flag;
    int tid = threadIdx.x;
    size_t tok0 = (size_t)blockIdx.x * 16;
    int w = tid >> 6, lane = tid & 63, quad = lane >> 4, l15 = lane & 15;
    bf16x8 areg[3];
    const u16* abase = g_h + (tok0 + l15) * HSTR + quad * 8;
    #pragma unroll
    for (int ks = 0; ks < 3; ++ks) areg[ks] = *(const bf16x8*)(abase + ks * 32);
    const int tab[5] = {0, 5, 10, 14, 18};
    for (int nt = tab[w]; nt < tab[w + 1]; ++nt) {
        f32x4 acc = {0.f, 0.f, 0.f, 0.f};
        const u16* bbase = g_f2w + (size_t)(nt * 16 + l15) * HSTR + quad * 8;
        #pragma unroll
        for (int ks = 0; ks < 3; ++ks) {
            bf16x8 bfr = *(const bf16x8*)(bbase + ks * 32);
            acc = __builtin_amdgcn_mfma_f32_16x16x32_bf16(areg[ks], bfr, acc, 0, 0, 0);
        }
        int o = nt * 16 + l15;
        float bias = ldin(fc2_b, o, bf);
        #pragma unroll
        for (int r = 0; r < 4; ++r) {
            size_t token = tok0 + quad * 4 + r;
            t2f[quad * 4 + r][o] = bits2f(g_t1[token * D + o]) + acc[r] + bias;
        }
    }
    __syncthreads();
    int b_ = (int)(tok0 >> 12), n0 = (int)(tok0 & 4095);
    for (int idx = tid; idx < D * 8; idx += 256) {
        int o = idx >> 3, tp = idx & 7;
        u32 v = (u32)f2bits(t2f[2 * tp][o]) | ((u32)f2bits(t2f[2 * tp + 1][o]) << 16);
        *(u32*)&g_t2b[((size_t)b_ * D + o) * NN + n0 + 2 * tp] = v;
    }
}

// ---- fold -> out (coalesced bf16 reads from transposed t2)
__global__ void k_fold(void* __restrict__ out) {
    int bf = g_flag;
    int idx = blockIdx.x * blockDim.x + threadIdx.x;
    if (idx >= BB * CCH * HH * WW) return;
    int xx = idx % WW;
    int y = (idx / WW) % HH;
    int c = (idx / (WW * HH)) % CCH;
    int b = idx / (WW * HH * CCH);
    const u16* base = g_t2b + ((size_t)b * D + c * 9) * NN;
    float s = 0.f;
    #pragma unroll
    for (int i = 0; i < 3; ++i) {
        int sy = y + 1 - i;
        if (sy < 0 || sy >= HH) continue;
        #pragma unroll
        for (int j = 0; j < 3; ++j) {
            int sx = xx + 1 - j;
            if (sx < 0 || sx >= WW) continue;
            s += bits2f(base[(size_t)(i * 3 + j) * NN + sy * WW + sx]);
        }
    }
    if (bf) ((bf16*)out)[idx] = __float2bfloat16(s);
    else    ((float*)out)[idx] = s;
}

extern "C" void kernel_launch(void* const* d_in, const int* in_sizes, int n_in,
                              void* d_out, int out_size, void* d_ws, size_t ws_size,
                              hipStream_t stream) {
    const void* x        = d_in[0];
    const void* ln1_w    = d_in[1];
    const void* ln1_b    = d_in[2];
    const void* reduce_w = d_in[3];
    const void* qkv_w    = d_in[4];
    const void* proj_w   = d_in[5];
    const void* proj_b   = d_in[6];
    const void* ln2_w    = d_in[7];
    const void* ln2_b    = d_in[8];
    const void* fc1_w    = d_in[9];
    const void* fc1_b    = d_in[10];
    const void* fc2_w    = d_in[11];
    const void* fc2_b    = d_in[12];

    k_prep        <<<DQ + RSB + PATCHB, 256, 0, stream>>>(x, qkv_w, reduce_w, proj_w, fc1_w, fc2_w);
    k_ln_qkv      <<<BB * NN / 16, 256, 0, stream>>>(ln1_w, ln1_b);
    k_attn        <<<2 * BB * NH * SPLIT * 8, 128, 0, stream>>>();
    k_proj_ln_fc1 <<<BB * NN / 16, 256, 0, stream>>>(proj_b, ln2_w, ln2_b, fc1_b);
    k_fc2         <<<BB * NN / 16, 256, 0, stream>>>(fc2_b);
    k_fold        <<<(BB * CCH * HH * WW + 255) / 256, 256, 0, stream>>>(d_out);
}

// Round 17
// 205.078 us; speedup vs baseline: 1.1067x; 1.0638x over previous
//
#include <hip/hip_runtime.h>
#include <hip/hip_bf16.h>

typedef __hip_bfloat16 bf16;
typedef unsigned short u16;
typedef unsigned int u32;
typedef __attribute__((ext_vector_type(8))) short bf16x8;
typedef __attribute__((ext_vector_type(4))) float f32x4;

#define BB 4
#define CCH 32
#define HH 64
#define WW 64
#define NN 4096
#define D 288
#define DR 144
#define DQ 432
#define NH 8
#define HD 18
#define SPLIT 4
#define CHUNK 1024
#define KS 512
#define DH 72
#define SCALE_ 0.16666666666666666f
#define QSCALE 0.24044917348149343f   // SCALE_ * log2(e)
#define EPS_ 1e-5f
#define ASTR 160
#define ATS 168
#define HSTR 96

__device__ __attribute__((aligned(16))) u16 g_Wcb[DQ * D];
__device__ __attribute__((aligned(16))) u16 g_pw[D * ASTR];
__device__ __attribute__((aligned(16))) u16 g_f1w[HSTR * D];
__device__ __attribute__((aligned(16))) u16 g_f2w[D * HSTR];
__device__ __attribute__((aligned(16))) u16 g_q[(size_t)BB * NH * NN * 32];
__device__ __attribute__((aligned(16))) u16 g_k[(size_t)BB * NH * NN * 32];
__device__ __attribute__((aligned(16))) u16 g_vt[(size_t)BB * NH * SPLIT * 32 * CHUNK];
__device__ __attribute__((aligned(16))) float g_part[2 * (size_t)BB * NH * NN * 20];
__device__ __attribute__((aligned(16))) u16 g_h[(size_t)BB * NN * HSTR];
__device__ __attribute__((aligned(16))) u16 g_t0[(size_t)BB * NN * D];
__device__ __attribute__((aligned(16))) u16 g_t1[(size_t)BB * NN * D];
__device__ __attribute__((aligned(16))) u16 g_t2b[(size_t)BB * D * NN];
__device__ int   g_flag;

__device__ __forceinline__ float b2f(bf16 v) { return __bfloat162float(v); }
__device__ __forceinline__ float bits2f(u16 u) { return __uint_as_float(((u32)u) << 16); }
__device__ __forceinline__ u16 f2bits(float f) {
    u32 u = __float_as_uint(f);
    return (u16)((u + 0x7FFF + ((u >> 16) & 1)) >> 16);
}
__device__ __forceinline__ float ldin(const void* p, size_t i, int isbf) {
    return isbf ? b2f(((const bf16*)p)[i]) : ((const float*)p)[i];
}

#define RS  (D * ASTR + HSTR * D + D * HSTR)
#define RS2 (RS + BB * NH * SPLIT * CHUNK)
#define RSB ((RS2 + 255) / 256)
#define PATCHB (BB * HH)

// ---- prep: dtype detect + Wc GEMM + weight staging + vt ones row + patch extract
__global__ void k_prep(const void* __restrict__ x, const void* __restrict__ qkv_w,
                       const void* __restrict__ reduce_w, const void* __restrict__ proj_w,
                       const void* __restrict__ fc1_w, const void* __restrict__ fc2_w) {
    __shared__ int cnt4[4];
    __shared__ float qw[DR];
    __shared__ float slab[32 * 3 * 66];
    int tid = threadIdx.x;
    {
        const u16* u = (const u16*)x;
        int c = 0;
        for (int i = tid; i < 2048; i += 256) c += (((u[i] >> 7) & 0xFF) >= 0x90);
        for (int o = 32; o; o >>= 1) c += __shfl_xor(c, o);
        if ((tid & 63) == 0) cnt4[tid >> 6] = c;
    }
    __syncthreads();
    int bf = (cnt4[0] + cnt4[1] + cnt4[2] + cnt4[3]) < 32;
    if (tid == 0 && blockIdx.x == 0) g_flag = bf;

    int bid = blockIdx.x;
    if (bid < DQ) {
        int o = bid;
        if (tid < DR) qw[tid] = ldin(qkv_w, (size_t)o * DR + tid, bf);
        __syncthreads();
        for (int col = tid; col < D; col += 256) {
            float s0 = 0.f, s1 = 0.f;
            #pragma unroll 4
            for (int j = 0; j < DR; j += 2) {
                s0 += qw[j] * ldin(reduce_w, (size_t)j * D + col, bf);
                s1 += qw[j + 1] * ldin(reduce_w, (size_t)(j + 1) * D + col, bf);
            }
            g_Wcb[(size_t)o * D + col] = f2bits(s0 + s1);
        }
    } else if (bid < DQ + RSB) {
        int idx = (bid - DQ) * 256 + tid;
        if (idx < D * ASTR) {
            int o = idx / ASTR, j = idx % ASTR;
            g_pw[idx] = (j < DR) ? f2bits(ldin(proj_w, (size_t)o * DR + j, bf)) : (u16)0;
        } else if (idx < D * ASTR + HSTR * D) {
            int t = idx - D * ASTR;
            int o = t / D;
            g_f1w[t] = (o < DH) ? f2bits(ldin(fc1_w, (size_t)t, bf)) : (u16)0;
        } else if (idx < RS) {
            int t = idx - D * ASTR - HSTR * D;
            int o = t / HSTR, j = t % HSTR;
            g_f2w[t] = (j < DH) ? f2bits(ldin(fc2_w, (size_t)o * DH + j, bf)) : (u16)0;
        } else if (idx < RS2) {
            int t = idx - RS;
            int bhs = t >> 10, n = t & 1023;
            g_vt[((size_t)bhs * 32 + 18) * CHUNK + n] = 0x3F80;  // bf16 1.0
        }
    } else {
        int pb = bid - DQ - RSB;
        int b = pb >> 6, y = pb & 63;
        for (int idx = tid; idx < 32 * 3 * 66; idx += 256) {
            int c = idx / 198, rem = idx % 198;
            int ki = rem / 66, col = rem % 66 - 1;
            int sy = y + ki - 1;
            float v = 0.f;
            if (col >= 0 && col < 64 && sy >= 0 && sy < 64)
                v = ldin(x, ((size_t)(b * CCH + c) * HH + sy) * WW + col, bf);
            slab[idx] = v;
        }
        __syncthreads();
        size_t obase = ((size_t)b * NN + y * 64) * D;
        for (int idx = tid; idx < 64 * D; idx += 256) {
            int t = idx / D, f = idx % D;
            int c = f / 9, k = f % 9, ki = k / 3, kj = k % 3;
            g_t0[obase + idx] = f2bits(slab[c * 198 + ki * 66 + t + kj]);
        }
    }
}

// ---- LN1 + qkv GEMM; block = 32 tokens, dual A-tiles per B-load
__global__ void k_ln_qkv(const void* __restrict__ lnw, const void* __restrict__ lnb) {
    __shared__ __attribute__((aligned(16))) u16 xln[32 * 296];
    __shared__ float lnwf[D], lnbf[D];
    __shared__ float smu[32], srs[32];
    __shared__ u16 buf[3][144][32];
    int bf = g_flag;
    int tid = threadIdx.x;
    size_t tok0 = (size_t)blockIdx.x * 32;
    for (int i = tid; i < D; i += 256) { lnwf[i] = ldin(lnw, i, bf); lnbf[i] = ldin(lnb, i, bf); }
    {   // stats: 8 threads per token, 36 elems (18 dwords) each
        int tt = tid >> 3, p = tid & 7;
        const u32* pr = (const u32*)(g_t0 + (tok0 + tt) * D + p * 36);
        float s = 0.f, q = 0.f;
        #pragma unroll
        for (int j = 0; j < 18; ++j) {
            u32 v = pr[j];
            float a = bits2f((u16)(v & 0xFFFF)), b = bits2f((u16)(v >> 16));
            s += a + b; q += a * a + b * b;
        }
        #pragma unroll
        for (int o = 1; o < 8; o <<= 1) { s += __shfl_xor(s, o); q += __shfl_xor(q, o); }
        if (p == 0) {
            float mu = s / D;
            smu[tt] = mu;
            srs[tt] = rsqrtf(q / D - mu * mu + EPS_);
        }
    }
    __syncthreads();
    for (int idx = tid; idx < 32 * 144; idx += 256) {
        int t = idx / 144, dw = idx % 144;
        u32 v = *(const u32*)(g_t0 + (tok0 + t) * D + 2 * dw);
        float mu = smu[t], rs = srs[t];
        int f = 2 * dw;
        float a = (bits2f((u16)(v & 0xFFFF)) - mu) * rs * lnwf[f] + lnbf[f];
        float b = (bits2f((u16)(v >> 16)) - mu) * rs * lnwf[f + 1] + lnbf[f + 1];
        *(u32*)&xln[t * 296 + f] = (u32)f2bits(a) | ((u32)f2bits(b) << 16);
    }
    __syncthreads();
    int w = tid >> 6, lane = tid & 63, quad = lane >> 4, l15 = lane & 15;
    bf16x8 areg0[9], areg1[9];
    {
        const u16* a0 = xln + l15 * 296 + quad * 8;
        const u16* a1 = xln + (16 + l15) * 296 + quad * 8;
        #pragma unroll
        for (int ks = 0; ks < 9; ++ks) {
            areg0[ks] = *(const bf16x8*)(a0 + ks * 32);
            areg1[ks] = *(const bf16x8*)(a1 + ks * 32);
        }
    }
    int nt0 = w * 7, nt1 = (nt0 + 7 > 27) ? 27 : nt0 + 7;
    for (int nt = nt0; nt < nt1; ++nt) {
        f32x4 acc0 = {0.f, 0.f, 0.f, 0.f}, acc1 = {0.f, 0.f, 0.f, 0.f};
        const u16* bbase = g_Wcb + (size_t)(nt * 16 + l15) * D + quad * 8;
        #pragma unroll
        for (int ks = 0; ks < 9; ++ks) {
            bf16x8 bfr = *(const bf16x8*)(bbase + ks * 32);
            acc0 = __builtin_amdgcn_mfma_f32_16x16x32_bf16(areg0[ks], bfr, acc0, 0, 0, 0);
            acc1 = __builtin_amdgcn_mfma_f32_16x16x32_bf16(areg1[ks], bfr, acc1, 0, 0, 0);
        }
        int o = nt * 16 + l15;
        int which = o / DR, rem = o % DR;
        #pragma unroll
        for (int r = 0; r < 4; ++r) {
            buf[which][rem][quad * 4 + r] = f2bits(which == 0 ? acc0[r] * QSCALE : acc0[r]);
            buf[which][rem][16 + quad * 4 + r] = f2bits(which == 0 ? acc1[r] * QSCALE : acc1[r]);
        }
    }
    __syncthreads();
    {
        int b_ = (int)(tok0 >> 12);
        int n0 = (int)(tok0 & 4095);
        int sIdx = n0 >> 10, nc = n0 & 1023;
        // q & k: u32-packed, coalesced
        for (int idx = tid; idx < 2 * 8 * 32 * 9; idx += 256) {
            int which = idx / 2304;
            int r2 = idx - which * 2304;
            int h = r2 / 288, r3 = r2 % 288, t = r3 / 9, dw = r3 % 9;
            u32 lo = buf[which][h * 18 + 2 * dw][t];
            u32 hi = buf[which][h * 18 + 2 * dw + 1][t];
            u16* dst = (which ? g_k : g_q) + ((size_t)(b_ * NH + h) * NN + n0 + t) * 32 + 2 * dw;
            *(u32*)dst = lo | (hi << 16);
        }
        // v: u32-packed token pairs
        for (int idx = tid; idx < 144 * 16; idx += 256) {
            int rem = idx >> 4, tp = idx & 15;
            int hh = rem / HD, dd = rem % HD;
            u32 lo = buf[2][rem][2 * tp];
            u32 hi = buf[2][rem][2 * tp + 1];
            size_t voff = (((size_t)(b_ * NH + hh) * SPLIT + sIdx) * 32 + dd) * CHUNK + nc + 2 * tp;
            *(u32*)&g_vt[voff] = lo | (hi << 16);
        }
    }
}

// ---- MFMA flash attention, 2-way split-K (unchanged)
#define PSTR 72
__global__ __launch_bounds__(128) void k_attn() {
    __shared__ __attribute__((aligned(16))) u16 Pl[2][4][16 * PSTR];
    int bid = blockIdx.x;
    int chunk = bid & 127;
    int qblk = (bid >> 7) & 7;
    int ksl = bid >> 10;
    int s = chunk & 3, bh = chunk >> 2;
    int tid = threadIdx.x;
    int w = tid >> 6, lane = tid & 63, quad = lane >> 4, l15 = lane & 15;

    size_t rowbase = (size_t)bh * NN + s * CHUNK;
    size_t vtbase = ((size_t)bh * SPLIT + s) * 32 * CHUNK;
    const u16* kbase = g_k + rowbase * 32 + quad * 8;
    const u16* vbase = g_vt + vtbase + quad * 8;

    int qbase = qblk * 128 + w * 64;
    bf16x8 qf[4];
    #pragma unroll
    for (int t = 0; t < 4; ++t)
        qf[t] = *(const bf16x8*)(g_q + (rowbase + qbase + t * 16 + l15) * 32 + quad * 8);

    f32x4 accA[4], accB[4];
    #pragma unroll
    for (int t = 0; t < 4; ++t) {
        accA[t] = (f32x4){0.f, 0.f, 0.f, 0.f};
        accB[t] = (f32x4){0.f, 0.f, 0.f, 0.f};
    }

    int kt0 = ksl * KS;
    for (int kk = 0; kk < KS; kk += 64) {
        int kt = kt0 + kk;
        bf16x8 kf0 = *(const bf16x8*)(kbase + (size_t)(kt + 2 * l15) * 32);
        bf16x8 kf1 = *(const bf16x8*)(kbase + (size_t)(kt + 2 * l15 + 1) * 32);
        bf16x8 kf2 = *(const bf16x8*)(kbase + (size_t)(kt + 32 + 2 * l15) * 32);
        bf16x8 kf3 = *(const bf16x8*)(kbase + (size_t)(kt + 33 + 2 * l15) * 32);
        bf16x8 vA0 = *(const bf16x8*)(vbase + (size_t)l15 * CHUNK + kt);
        bf16x8 vB0 = *(const bf16x8*)(vbase + (size_t)(16 + l15) * CHUNK + kt);
        bf16x8 vA1 = *(const bf16x8*)(vbase + (size_t)l15 * CHUNK + kt + 32);
        bf16x8 vB1 = *(const bf16x8*)(vbase + (size_t)(16 + l15) * CHUNK + kt + 32);
        f32x4 z = {0.f, 0.f, 0.f, 0.f};
        #pragma unroll
        for (int t = 0; t < 4; ++t) {
            u16* pw = Pl[w][t];
            f32x4 S0 = __builtin_amdgcn_mfma_f32_16x16x32_bf16(qf[t], kf0, z, 0, 0, 0);
            f32x4 S1 = __builtin_amdgcn_mfma_f32_16x16x32_bf16(qf[t], kf1, z, 0, 0, 0);
            f32x4 S2 = __builtin_amdgcn_mfma_f32_16x16x32_bf16(qf[t], kf2, z, 0, 0, 0);
            f32x4 S3 = __builtin_amdgcn_mfma_f32_16x16x32_bf16(qf[t], kf3, z, 0, 0, 0);
            #pragma unroll
            for (int r = 0; r < 4; ++r) {
                float p0 = exp2f(S0[r]), p1 = exp2f(S1[r]);
                float p2 = exp2f(S2[r]), p3 = exp2f(S3[r]);
                u32 w0 = __builtin_amdgcn_perm(__float_as_uint(p1), __float_as_uint(p0), 0x07060302u);
                u32 w1 = __builtin_amdgcn_perm(__float_as_uint(p3), __float_as_uint(p2), 0x07060302u);
                *(u32*)&pw[(quad * 4 + r) * PSTR + 2 * l15] = w0;
                *(u32*)&pw[(quad * 4 + r) * PSTR + 32 + 2 * l15] = w1;
            }
        }
        #pragma unroll
        for (int t = 0; t < 4; ++t) {
            const u16* pw = Pl[w][t];
            bf16x8 pf0 = *(const bf16x8*)&pw[l15 * PSTR + quad * 8];
            bf16x8 pf1 = *(const bf16x8*)&pw[l15 * PSTR + 32 + quad * 8];
            accA[t] = __builtin_amdgcn_mfma_f32_16x16x32_bf16(pf0, vA0, accA[t], 0, 0, 0);
            accB[t] = __builtin_amdgcn_mfma_f32_16x16x32_bf16(pf0, vB0, accB[t], 0, 0, 0);
            accA[t] = __builtin_amdgcn_mfma_f32_16x16x32_bf16(pf1, vA1, accA[t], 0, 0, 0);
            accB[t] = __builtin_amdgcn_mfma_f32_16x16x32_bf16(pf1, vB1, accB[t], 0, 0, 0);
        }
    }
    float* pb = g_part + (((size_t)ksl * 32 + bh) * SPLIT + s) * (size_t)(CHUNK * 20);
    #pragma unroll
    for (int t = 0; t < 4; ++t) {
        #pragma unroll
        for (int r = 0; r < 4; ++r) {
            int tokenc = qbase + t * 16 + quad * 4 + r;
            float* row = pb + (size_t)tokenc * 20;
            row[l15] = accA[t][r];
            if (l15 < 3) row[16 + l15] = accB[t][r];
        }
    }
}

// ---- fused combine + proj + residual + LN2 + fc1 + relu; block = 32 tokens, dual A-tiles
__global__ void k_proj_ln_fc1(const void* __restrict__ proj_b, const void* __restrict__ lnw,
                              const void* __restrict__ lnb, const void* __restrict__ fc1_b) {
    __shared__ __attribute__((aligned(16))) u16 t1f[32 * 296];   // bf16 t1 tile
    __shared__ __attribute__((aligned(16))) u16 xln[32 * 296];
    __shared__ __attribute__((aligned(16))) u16 attnT[32 * ATS];
    __shared__ float lnwf[D], lnbf[D];
    __shared__ float smu[32], srs[32];
    int bf = g_flag;
    int tid = threadIdx.x;
    size_t tok0 = (size_t)blockIdx.x * 32;
    int w = tid >> 6, lane = tid & 63, quad = lane >> 4, l15 = lane & 15;
    for (int i = tid; i < D; i += 256) { lnwf[i] = ldin(lnw, i, bf); lnbf[i] = ldin(lnb, i, bf); }

    // phase 0: split-K combine -> attnT
    int b_ = (int)(tok0 >> 12);
    int s_ = ((int)tok0 & 4095) >> 10;
    int tc0 = (int)tok0 & 1023;
    for (int idx = tid; idx < 32 * (ATS - DR); idx += 256) {
        int t = idx / (ATS - DR), f = idx % (ATS - DR);
        attnT[t * ATS + DR + f] = 0;
    }
    {
        int t = tid >> 3, h = tid & 7;
        const float* p1 = g_part + (((size_t)(b_ * NH + h)) * SPLIT + s_) * (size_t)(CHUNK * 20)
                        + (size_t)(tc0 + t) * 20;
        const float* p2 = p1 + (size_t)32 * SPLIT * CHUNK * 20;
        f32x4 a0 = *(const f32x4*)p1,        c0 = *(const f32x4*)p2;
        f32x4 a1 = *(const f32x4*)(p1 + 4),  c1 = *(const f32x4*)(p2 + 4);
        f32x4 a2 = *(const f32x4*)(p1 + 8),  c2 = *(const f32x4*)(p2 + 8);
        f32x4 a3 = *(const f32x4*)(p1 + 12), c3 = *(const f32x4*)(p2 + 12);
        f32x4 a4 = *(const f32x4*)(p1 + 16), c4 = *(const f32x4*)(p2 + 16);
        float inv = 1.f / (a4[2] + c4[2]);
        u16* dst = attnT + t * ATS + h * HD;
        #pragma unroll
        for (int d = 0; d < 4; ++d) {
            dst[d]      = f2bits((a0[d] + c0[d]) * inv);
            dst[4 + d]  = f2bits((a1[d] + c1[d]) * inv);
            dst[8 + d]  = f2bits((a2[d] + c2[d]) * inv);
            dst[12 + d] = f2bits((a3[d] + c3[d]) * inv);
        }
        dst[16] = f2bits((a4[0] + c4[0]) * inv);
        dst[17] = f2bits((a4[1] + c4[1]) * inv);
    }
    __syncthreads();

    // phase A: proj + residual, dual A-tiles
    {
        bf16x8 areg0[5], areg1[5];
        const u16* a0 = attnT + l15 * ATS + quad * 8;
        const u16* a1 = attnT + (16 + l15) * ATS + quad * 8;
        #pragma unroll
        for (int ks = 0; ks < 5; ++ks) {
            areg0[ks] = *(const bf16x8*)(a0 + ks * 32);
            areg1[ks] = *(const bf16x8*)(a1 + ks * 32);
        }
        const int tab[5] = {0, 5, 10, 14, 18};
        for (int nt = tab[w]; nt < tab[w + 1]; ++nt) {
            f32x4 acc0 = {0.f, 0.f, 0.f, 0.f}, acc1 = {0.f, 0.f, 0.f, 0.f};
            const u16* bbase = g_pw + (size_t)(nt * 16 + l15) * ASTR + quad * 8;
            #pragma unroll
            for (int ks = 0; ks < 5; ++ks) {
                bf16x8 bfr = *(const bf16x8*)(bbase + ks * 32);
                acc0 = __builtin_amdgcn_mfma_f32_16x16x32_bf16(areg0[ks], bfr, acc0, 0, 0, 0);
                acc1 = __builtin_amdgcn_mfma_f32_16x16x32_bf16(areg1[ks], bfr, acc1, 0, 0, 0);
            }
            int o = nt * 16 + l15;
            float bias = ldin(proj_b, o, bf);
            #pragma unroll
            for (int r = 0; r < 4; ++r) {
                {
                    size_t token = tok0 + quad * 4 + r;
                    size_t off = token * D + o;
                    u16 vb = f2bits(bits2f(g_t0[off]) + acc0[r] + bias);
                    g_t1[off] = vb;
                    t1f[(quad * 4 + r) * 296 + o] = vb;
                }
                {
                    size_t token = tok0 + 16 + quad * 4 + r;
                    size_t off = token * D + o;
                    u16 vb = f2bits(bits2f(g_t0[off]) + acc1[r] + bias);
                    g_t1[off] = vb;
                    t1f[(16 + quad * 4 + r) * 296 + o] = vb;
                }
            }
        }
    }
    __syncthreads();
    {   // LN2 stats: 8 threads/token from bf16 t1f
        int tt = tid >> 3, p = tid & 7;
        const u32* src = (const u32*)&t1f[tt * 296 + p * 36];
        float s = 0.f, q = 0.f;
        #pragma unroll
        for (int j = 0; j < 18; ++j) {
            u32 v = src[j];
            float a = bits2f((u16)(v & 0xFFFF)), b = bits2f((u16)(v >> 16));
            s += a + b; q += a * a + b * b;
        }
        #pragma unroll
        for (int o = 1; o < 8; o <<= 1) { s += __shfl_xor(s, o); q += __shfl_xor(q, o); }
        if (p == 0) {
            float mu = s / D;
            smu[tt] = mu;
            srs[tt] = rsqrtf(q / D - mu * mu + EPS_);
        }
    }
    __syncthreads();
    for (int idx = tid; idx < 32 * 144; idx += 256) {
        int t = idx / 144, dw = idx % 144;
        int f = 2 * dw;
        u32 v = *(const u32*)&t1f[t * 296 + f];
        float mu = smu[t], rs = srs[t];
        float a = (bits2f((u16)(v & 0xFFFF)) - mu) * rs * lnwf[f] + lnbf[f];
        float b = (bits2f((u16)(v >> 16)) - mu) * rs * lnwf[f + 1] + lnbf[f + 1];
        *(u32*)&xln[t * 296 + f] = (u32)f2bits(a) | ((u32)f2bits(b) << 16);
    }
    __syncthreads();
    {   // fc1 + relu, dual A-tiles
        bf16x8 areg0[9], areg1[9];
        const u16* a0 = xln + l15 * 296 + quad * 8;
        const u16* a1 = xln + (16 + l15) * 296 + quad * 8;
        #pragma unroll
        for (int ks = 0; ks < 9; ++ks) {
            areg0[ks] = *(const bf16x8*)(a0 + ks * 32);
            areg1[ks] = *(const bf16x8*)(a1 + ks * 32);
        }
        const int tab2[5] = {0, 2, 4, 5, 6};
        for (int nt = tab2[w]; nt < tab2[w + 1]; ++nt) {
            f32x4 acc0 = {0.f, 0.f, 0.f, 0.f}, acc1 = {0.f, 0.f, 0.f, 0.f};
            const u16* bbase = g_f1w + (size_t)(nt * 16 + l15) * D + quad * 8;
            #pragma unroll
            for (int ks = 0; ks < 9; ++ks) {
                bf16x8 bfr = *(const bf16x8*)(bbase + ks * 32);
                acc0 = __builtin_amdgcn_mfma_f32_16x16x32_bf16(areg0[ks], bfr, acc0, 0, 0, 0);
                acc1 = __builtin_amdgcn_mfma_f32_16x16x32_bf16(areg1[ks], bfr, acc1, 0, 0, 0);
            }
            int o = nt * 16 + l15;
            float bias = (o < DH) ? ldin(fc1_b, o, bf) : 0.f;
            #pragma unroll
            for (int r = 0; r < 4; ++r) {
                g_h[(tok0 + quad * 4 + r) * HSTR + o] = f2bits(fmaxf(acc0[r] + bias, 0.f));
                g_h[(tok0 + 16 + quad * 4 + r) * HSTR + o] = f2bits(fmaxf(acc1[r] + bias, 0.f));
            }
        }
    }
}

// ---- fc2 + residual -> g_t2b transposed; block = 32 tokens, dual A-tiles
__global__ void k_fc2(const void* __restrict__ fc2_b) {
    __shared__ float t2f[32][293];
    int bf = g_flag;
    int tid = threadIdx.x;
    size_t tok0 = (size_t)blockIdx.x * 32;
    int w = tid >> 6, lane = tid & 63, quad = lane >> 4, l15 = lane & 15;
    bf16x8 areg0[3], areg1[3];
    {
        const u16* a0 = g_h + (tok0 + l15) * HSTR + quad * 8;
        const u16* a1 = g_h + (tok0 + 16 + l15) * HSTR + quad * 8;
        #pragma unroll
        for (int ks = 0; ks < 3; ++ks) {
            areg0[ks] = *(const bf16x8*)(a0 + ks * 32);
            areg1[ks] = *(const bf16x8*)(a1 + ks * 32);
        }
    }
    const int tab[5] = {0, 5, 10, 14, 18};
    for (int nt = tab[w]; nt < tab[w + 1]; ++nt) {
        f32x4 acc0 = {0.f, 0.f, 0.f, 0.f}, acc1 = {0.f, 0.f, 0.f, 0.f};
        const u16* bbase = g_f2w + (size_t)(nt * 16 + l15) * HSTR + quad * 8;
        #pragma unroll
        for (int ks = 0; ks < 3; ++ks) {
            bf16x8 bfr = *(const bf16x8*)(bbase + ks * 32);
            acc0 = __builtin_amdgcn_mfma_f32_16x16x32_bf16(areg0[ks], bfr, acc0, 0, 0, 0);
            acc1 = __builtin_amdgcn_mfma_f32_16x16x32_bf16(areg1[ks], bfr, acc1, 0, 0, 0);
        }
        int o = nt * 16 + l15;
        float bias = ldin(fc2_b, o, bf);
        #pragma unroll
        for (int r = 0; r < 4; ++r) {
            t2f[quad * 4 + r][o] = bits2f(g_t1[(tok0 + quad * 4 + r) * D + o]) + acc0[r] + bias;
            t2f[16 + quad * 4 + r][o] = bits2f(g_t1[(tok0 + 16 + quad * 4 + r) * D + o]) + acc1[r] + bias;
        }
    }
    __syncthreads();
    int b_ = (int)(tok0 >> 12), n0 = (int)(tok0 & 4095);
    for (int idx = tid; idx < D * 16; idx += 256) {
        int o = idx >> 4, tp = idx & 15;
        u32 v = (u32)f2bits(t2f[2 * tp][o]) | ((u32)f2bits(t2f[2 * tp + 1][o]) << 16);
        *(u32*)&g_t2b[((size_t)b_ * D + o) * NN + n0 + 2 * tp] = v;
    }
}

// ---- fold -> out
__global__ void k_fold(void* __restrict__ out) {
    int bf = g_flag;
    int idx = blockIdx.x * blockDim.x + threadIdx.x;
    if (idx >= BB * CCH * HH * WW) return;
    int xx = idx % WW;
    int y = (idx / WW) % HH;
    int c = (idx / (WW * HH)) % CCH;
    int b = idx / (WW * HH * CCH);
    const u16* base = g_t2b + ((size_t)b * D + c * 9) * NN;
    float s = 0.f;
    #pragma unroll
    for (int i = 0; i < 3; ++i) {
        int sy = y + 1 - i;
        if (sy < 0 || sy >= HH) continue;
        #pragma unroll
        for (int j = 0; j < 3; ++j) {
            int sx = xx + 1 - j;
            if (sx < 0 || sx >= WW) continue;
            s += bits2f(base[(size_t)(i * 3 + j) * NN + sy * WW + sx]);
        }
    }
    if (bf) ((bf16*)out)[idx] = __float2bfloat16(s);
    else    ((float*)out)[idx] = s;
}

extern "C" void kernel_launch(void* const* d_in, const int* in_sizes, int n_in,
                              void* d_out, int out_size, void* d_ws, size_t ws_size,
                              hipStream_t stream) {
    const void* x        = d_in[0];
    const void* ln1_w    = d_in[1];
    const void* ln1_b    = d_in[2];
    const void* reduce_w = d_in[3];
    const void* qkv_w    = d_in[4];
    const void* proj_w   = d_in[5];
    const void* proj_b   = d_in[6];
    const void* ln2_w    = d_in[7];
    const void* ln2_b    = d_in[8];
    const void* fc1_w    = d_in[9];
    const void* fc1_b    = d_in[10];
    const void* fc2_w    = d_in[11];
    const void* fc2_b    = d_in[12];

    k_prep        <<<DQ + RSB + PATCHB, 256, 0, stream>>>(x, qkv_w, reduce_w, proj_w, fc1_w, fc2_w);
    k_ln_qkv      <<<BB * NN / 32, 256, 0, stream>>>(ln1_w, ln1_b);
    k_attn        <<<2 * BB * NH * SPLIT * 8, 128, 0, stream>>>();
    k_proj_ln_fc1 <<<BB * NN / 32, 256, 0, stream>>>(proj_b, ln2_w, ln2_b, fc1_b);
    k_fc2         <<<BB * NN / 32, 256, 0, stream>>>(fc2_b);
    k_fold        <<<(BB * CCH * HH * WW + 255) / 256, 256, 0, stream>>>(d_out);
}

// Round 18
// 198.327 us; speedup vs baseline: 1.1444x; 1.0340x over previous
//
#include <hip/hip_runtime.h>
#include <hip/hip_bf16.h>

typedef __hip_bfloat16 bf16;
typedef unsigned short u16;
typedef unsigned int u32;
typedef __attribute__((ext_vector_type(8))) short bf16x8;
typedef __attribute__((ext_vector_type(4))) float f32x4;

#define BB 4
#define CCH 32
#define HH 64
#define WW 64
#define NN 4096
#define D 288
#define DR 144
#define DQ 432
#define NH 8
#define HD 18
#define SPLIT 4
#define CHUNK 1024
#define KS 512
#define DH 72
#define SCALE_ 0.16666666666666666f
#define QSCALE 0.24044917348149343f   // SCALE_ * log2(e)
#define EPS_ 1e-5f
#define ASTR 160
#define ATS 168
#define HSTR 96

__device__ __attribute__((aligned(16))) u16 g_Wcb[DQ * D];
__device__ __attribute__((aligned(16))) u16 g_pw[D * ASTR];
__device__ __attribute__((aligned(16))) u16 g_f1w[HSTR * D];
__device__ __attribute__((aligned(16))) u16 g_f2w[D * HSTR];
__device__ __attribute__((aligned(16))) u16 g_q[(size_t)BB * NH * NN * 32];
__device__ __attribute__((aligned(16))) u16 g_k[(size_t)BB * NH * NN * 32];
__device__ __attribute__((aligned(16))) u16 g_vt[(size_t)BB * NH * SPLIT * 32 * CHUNK];
__device__ __attribute__((aligned(16))) float g_part[2 * (size_t)BB * NH * NN * 20];
__device__ __attribute__((aligned(16))) u16 g_t0[(size_t)BB * NN * D];
__device__ __attribute__((aligned(16))) u16 g_t2b[(size_t)BB * D * NN];
__device__ int   g_flag;

__device__ __forceinline__ float b2f(bf16 v) { return __bfloat162float(v); }
__device__ __forceinline__ float bits2f(u16 u) { return __uint_as_float(((u32)u) << 16); }
__device__ __forceinline__ u16 f2bits(float f) {
    u32 u = __float_as_uint(f);
    return (u16)((u + 0x7FFF + ((u >> 16) & 1)) >> 16);
}
__device__ __forceinline__ float ldin(const void* p, size_t i, int isbf) {
    return isbf ? b2f(((const bf16*)p)[i]) : ((const float*)p)[i];
}

#define RS  (D * ASTR + HSTR * D + D * HSTR)
#define RS2 (RS + BB * NH * SPLIT * CHUNK)
#define RSB ((RS2 + 255) / 256)
#define PATCHB (BB * HH)

// ---- prep: dtype detect + Wc GEMM + weight staging + vt ones row + patch extract
__global__ void k_prep(const void* __restrict__ x, const void* __restrict__ qkv_w,
                       const void* __restrict__ reduce_w, const void* __restrict__ proj_w,
                       const void* __restrict__ fc1_w, const void* __restrict__ fc2_w) {
    __shared__ int cnt4[4];
    __shared__ float qw[DR];
    __shared__ float slab[32 * 3 * 66];
    int tid = threadIdx.x;
    {
        const u16* u = (const u16*)x;
        int c = 0;
        for (int i = tid; i < 2048; i += 256) c += (((u[i] >> 7) & 0xFF) >= 0x90);
        for (int o = 32; o; o >>= 1) c += __shfl_xor(c, o);
        if ((tid & 63) == 0) cnt4[tid >> 6] = c;
    }
    __syncthreads();
    int bf = (cnt4[0] + cnt4[1] + cnt4[2] + cnt4[3]) < 32;
    if (tid == 0 && blockIdx.x == 0) g_flag = bf;

    int bid = blockIdx.x;
    if (bid < DQ) {
        int o = bid;
        if (tid < DR) qw[tid] = ldin(qkv_w, (size_t)o * DR + tid, bf);
        __syncthreads();
        for (int col = tid; col < D; col += 256) {
            float s0 = 0.f, s1 = 0.f;
            #pragma unroll 4
            for (int j = 0; j < DR; j += 2) {
                s0 += qw[j] * ldin(reduce_w, (size_t)j * D + col, bf);
                s1 += qw[j + 1] * ldin(reduce_w, (size_t)(j + 1) * D + col, bf);
            }
            g_Wcb[(size_t)o * D + col] = f2bits(s0 + s1);
        }
    } else if (bid < DQ + RSB) {
        int idx = (bid - DQ) * 256 + tid;
        if (idx < D * ASTR) {
            int o = idx / ASTR, j = idx % ASTR;
            g_pw[idx] = (j < DR) ? f2bits(ldin(proj_w, (size_t)o * DR + j, bf)) : (u16)0;
        } else if (idx < D * ASTR + HSTR * D) {
            int t = idx - D * ASTR;
            int o = t / D;
            g_f1w[t] = (o < DH) ? f2bits(ldin(fc1_w, (size_t)t, bf)) : (u16)0;
        } else if (idx < RS) {
            int t = idx - D * ASTR - HSTR * D;
            int o = t / HSTR, j = t % HSTR;
            g_f2w[t] = (j < DH) ? f2bits(ldin(fc2_w, (size_t)o * DH + j, bf)) : (u16)0;
        } else if (idx < RS2) {
            int t = idx - RS;
            int bhs = t >> 10, n = t & 1023;
            g_vt[((size_t)bhs * 32 + 18) * CHUNK + n] = 0x3F80;  // bf16 1.0
        }
    } else {
        int pb = bid - DQ - RSB;
        int b = pb >> 6, y = pb & 63;
        for (int idx = tid; idx < 32 * 3 * 66; idx += 256) {
            int c = idx / 198, rem = idx % 198;
            int ki = rem / 66, col = rem % 66 - 1;
            int sy = y + ki - 1;
            float v = 0.f;
            if (col >= 0 && col < 64 && sy >= 0 && sy < 64)
                v = ldin(x, ((size_t)(b * CCH + c) * HH + sy) * WW + col, bf);
            slab[idx] = v;
        }
        __syncthreads();
        size_t obase = ((size_t)b * NN + y * 64) * D;
        for (int idx = tid; idx < 64 * D; idx += 256) {
            int t = idx / D, f = idx % D;
            int c = f / 9, k = f % 9, ki = k / 3, kj = k % 3;
            g_t0[obase + idx] = f2bits(slab[c * 198 + ki * 66 + t + kj]);
        }
    }
}

// ---- LN1 + qkv GEMM; block = 32 tokens, dual A-tiles per B-load
__global__ void k_ln_qkv(const void* __restrict__ lnw, const void* __restrict__ lnb) {
    __shared__ __attribute__((aligned(16))) u16 xln[32 * 296];
    __shared__ float lnwf[D], lnbf[D];
    __shared__ float smu[32], srs[32];
    __shared__ u16 buf[3][144][32];
    int bf = g_flag;
    int tid = threadIdx.x;
    size_t tok0 = (size_t)blockIdx.x * 32;
    for (int i = tid; i < D; i += 256) { lnwf[i] = ldin(lnw, i, bf); lnbf[i] = ldin(lnb, i, bf); }
    {
        int tt = tid >> 3, p = tid & 7;
        const u32* pr = (const u32*)(g_t0 + (tok0 + tt) * D + p * 36);
        float s = 0.f, q = 0.f;
        #pragma unroll
        for (int j = 0; j < 18; ++j) {
            u32 v = pr[j];
            float a = bits2f((u16)(v & 0xFFFF)), b = bits2f((u16)(v >> 16));
            s += a + b; q += a * a + b * b;
        }
        #pragma unroll
        for (int o = 1; o < 8; o <<= 1) { s += __shfl_xor(s, o); q += __shfl_xor(q, o); }
        if (p == 0) {
            float mu = s / D;
            smu[tt] = mu;
            srs[tt] = rsqrtf(q / D - mu * mu + EPS_);
        }
    }
    __syncthreads();
    for (int idx = tid; idx < 32 * 144; idx += 256) {
        int t = idx / 144, dw = idx % 144;
        u32 v = *(const u32*)(g_t0 + (tok0 + t) * D + 2 * dw);
        float mu = smu[t], rs = srs[t];
        int f = 2 * dw;
        float a = (bits2f((u16)(v & 0xFFFF)) - mu) * rs * lnwf[f] + lnbf[f];
        float b = (bits2f((u16)(v >> 16)) - mu) * rs * lnwf[f + 1] + lnbf[f + 1];
        *(u32*)&xln[t * 296 + f] = (u32)f2bits(a) | ((u32)f2bits(b) << 16);
    }
    __syncthreads();
    int w = tid >> 6, lane = tid & 63, quad = lane >> 4, l15 = lane & 15;
    bf16x8 areg0[9], areg1[9];
    {
        const u16* a0 = xln + l15 * 296 + quad * 8;
        const u16* a1 = xln + (16 + l15) * 296 + quad * 8;
        #pragma unroll
        for (int ks = 0; ks < 9; ++ks) {
            areg0[ks] = *(const bf16x8*)(a0 + ks * 32);
            areg1[ks] = *(const bf16x8*)(a1 + ks * 32);
        }
    }
    int nt0 = w * 7, nt1 = (nt0 + 7 > 27) ? 27 : nt0 + 7;
    for (int nt = nt0; nt < nt1; ++nt) {
        f32x4 acc0 = {0.f, 0.f, 0.f, 0.f}, acc1 = {0.f, 0.f, 0.f, 0.f};
        const u16* bbase = g_Wcb + (size_t)(nt * 16 + l15) * D + quad * 8;
        #pragma unroll
        for (int ks = 0; ks < 9; ++ks) {
            bf16x8 bfr = *(const bf16x8*)(bbase + ks * 32);
            acc0 = __builtin_amdgcn_mfma_f32_16x16x32_bf16(areg0[ks], bfr, acc0, 0, 0, 0);
            acc1 = __builtin_amdgcn_mfma_f32_16x16x32_bf16(areg1[ks], bfr, acc1, 0, 0, 0);
        }
        int o = nt * 16 + l15;
        int which = o / DR, rem = o % DR;
        #pragma unroll
        for (int r = 0; r < 4; ++r) {
            buf[which][rem][quad * 4 + r] = f2bits(which == 0 ? acc0[r] * QSCALE : acc0[r]);
            buf[which][rem][16 + quad * 4 + r] = f2bits(which == 0 ? acc1[r] * QSCALE : acc1[r]);
        }
    }
    __syncthreads();
    {
        int b_ = (int)(tok0 >> 12);
        int n0 = (int)(tok0 & 4095);
        int sIdx = n0 >> 10, nc = n0 & 1023;
        for (int idx = tid; idx < 2 * 8 * 32 * 9; idx += 256) {
            int which = idx / 2304;
            int r2 = idx - which * 2304;
            int h = r2 / 288, r3 = r2 % 288, t = r3 / 9, dw = r3 % 9;
            u32 lo = buf[which][h * 18 + 2 * dw][t];
            u32 hi = buf[which][h * 18 + 2 * dw + 1][t];
            u16* dst = (which ? g_k : g_q) + ((size_t)(b_ * NH + h) * NN + n0 + t) * 32 + 2 * dw;
            *(u32*)dst = lo | (hi << 16);
        }
        for (int idx = tid; idx < 144 * 16; idx += 256) {
            int rem = idx >> 4, tp = idx & 15;
            int hh = rem / HD, dd = rem % HD;
            u32 lo = buf[2][rem][2 * tp];
            u32 hi = buf[2][rem][2 * tp + 1];
            size_t voff = (((size_t)(b_ * NH + hh) * SPLIT + sIdx) * 32 + dd) * CHUNK + nc + 2 * tp;
            *(u32*)&g_vt[voff] = lo | (hi << 16);
        }
    }
}

// ---- MFMA flash attention, 2-way split-K (unchanged)
#define PSTR 72
__global__ __launch_bounds__(128) void k_attn() {
    __shared__ __attribute__((aligned(16))) u16 Pl[2][4][16 * PSTR];
    int bid = blockIdx.x;
    int chunk = bid & 127;
    int qblk = (bid >> 7) & 7;
    int ksl = bid >> 10;
    int s = chunk & 3, bh = chunk >> 2;
    int tid = threadIdx.x;
    int w = tid >> 6, lane = tid & 63, quad = lane >> 4, l15 = lane & 15;

    size_t rowbase = (size_t)bh * NN + s * CHUNK;
    size_t vtbase = ((size_t)bh * SPLIT + s) * 32 * CHUNK;
    const u16* kbase = g_k + rowbase * 32 + quad * 8;
    const u16* vbase = g_vt + vtbase + quad * 8;

    int qbase = qblk * 128 + w * 64;
    bf16x8 qf[4];
    #pragma unroll
    for (int t = 0; t < 4; ++t)
        qf[t] = *(const bf16x8*)(g_q + (rowbase + qbase + t * 16 + l15) * 32 + quad * 8);

    f32x4 accA[4], accB[4];
    #pragma unroll
    for (int t = 0; t < 4; ++t) {
        accA[t] = (f32x4){0.f, 0.f, 0.f, 0.f};
        accB[t] = (f32x4){0.f, 0.f, 0.f, 0.f};
    }

    int kt0 = ksl * KS;
    for (int kk = 0; kk < KS; kk += 64) {
        int kt = kt0 + kk;
        bf16x8 kf0 = *(const bf16x8*)(kbase + (size_t)(kt + 2 * l15) * 32);
        bf16x8 kf1 = *(const bf16x8*)(kbase + (size_t)(kt + 2 * l15 + 1) * 32);
        bf16x8 kf2 = *(const bf16x8*)(kbase + (size_t)(kt + 32 + 2 * l15) * 32);
        bf16x8 kf3 = *(const bf16x8*)(kbase + (size_t)(kt + 33 + 2 * l15) * 32);
        bf16x8 vA0 = *(const bf16x8*)(vbase + (size_t)l15 * CHUNK + kt);
        bf16x8 vB0 = *(const bf16x8*)(vbase + (size_t)(16 + l15) * CHUNK + kt);
        bf16x8 vA1 = *(const bf16x8*)(vbase + (size_t)l15 * CHUNK + kt + 32);
        bf16x8 vB1 = *(const bf16x8*)(vbase + (size_t)(16 + l15) * CHUNK + kt + 32);
        f32x4 z = {0.f, 0.f, 0.f, 0.f};
        #pragma unroll
        for (int t = 0; t < 4; ++t) {
            u16* pw = Pl[w][t];
            f32x4 S0 = __builtin_amdgcn_mfma_f32_16x16x32_bf16(qf[t], kf0, z, 0, 0, 0);
            f32x4 S1 = __builtin_amdgcn_mfma_f32_16x16x32_bf16(qf[t], kf1, z, 0, 0, 0);
            f32x4 S2 = __builtin_amdgcn_mfma_f32_16x16x32_bf16(qf[t], kf2, z, 0, 0, 0);
            f32x4 S3 = __builtin_amdgcn_mfma_f32_16x16x32_bf16(qf[t], kf3, z, 0, 0, 0);
            #pragma unroll
            for (int r = 0; r < 4; ++r) {
                float p0 = exp2f(S0[r]), p1 = exp2f(S1[r]);
                float p2 = exp2f(S2[r]), p3 = exp2f(S3[r]);
                u32 w0 = __builtin_amdgcn_perm(__float_as_uint(p1), __float_as_uint(p0), 0x07060302u);
                u32 w1 = __builtin_amdgcn_perm(__float_as_uint(p3), __float_as_uint(p2), 0x07060302u);
                *(u32*)&pw[(quad * 4 + r) * PSTR + 2 * l15] = w0;
                *(u32*)&pw[(quad * 4 + r) * PSTR + 32 + 2 * l15] = w1;
            }
        }
        #pragma unroll
        for (int t = 0; t < 4; ++t) {
            const u16* pw = Pl[w][t];
            bf16x8 pf0 = *(const bf16x8*)&pw[l15 * PSTR + quad * 8];
            bf16x8 pf1 = *(const bf16x8*)&pw[l15 * PSTR + 32 + quad * 8];
            accA[t] = __builtin_amdgcn_mfma_f32_16x16x32_bf16(pf0, vA0, accA[t], 0, 0, 0);
            accB[t] = __builtin_amdgcn_mfma_f32_16x16x32_bf16(pf0, vB0, accB[t], 0, 0, 0);
            accA[t] = __builtin_amdgcn_mfma_f32_16x16x32_bf16(pf1, vA1, accA[t], 0, 0, 0);
            accB[t] = __builtin_amdgcn_mfma_f32_16x16x32_bf16(pf1, vB1, accB[t], 0, 0, 0);
        }
    }
    float* pb = g_part + (((size_t)ksl * 32 + bh) * SPLIT + s) * (size_t)(CHUNK * 20);
    #pragma unroll
    for (int t = 0; t < 4; ++t) {
        #pragma unroll
        for (int r = 0; r < 4; ++r) {
            int tokenc = qbase + t * 16 + quad * 4 + r;
            float* row = pb + (size_t)tokenc * 20;
            row[l15] = accA[t][r];
            if (l15 < 3) row[16 + l15] = accB[t][r];
        }
    }
}

// ---- fused combine + proj + residual + LN2 + fc1 + relu + fc2 + residual
//      block = 32 tokens; t1/h never touch global; t2 stage reuses xln
__global__ void k_proj_mlp(const void* __restrict__ proj_b, const void* __restrict__ lnw,
                           const void* __restrict__ lnb, const void* __restrict__ fc1_b,
                           const void* __restrict__ fc2_b) {
    __shared__ __attribute__((aligned(16))) u16 t1f[32 * 296];   // bf16 t1 tile
    __shared__ __attribute__((aligned(16))) u16 xln[32 * 296];   // LN2 out, reused for t2 stage
    __shared__ __attribute__((aligned(16))) u16 attnT[32 * ATS];
    __shared__ __attribute__((aligned(16))) u16 hbuf[32 * HSTR];
    __shared__ float lnwf[D], lnbf[D];
    __shared__ float smu[32], srs[32];
    int bf = g_flag;
    int tid = threadIdx.x;
    size_t tok0 = (size_t)blockIdx.x * 32;
    int w = tid >> 6, lane = tid & 63, quad = lane >> 4, l15 = lane & 15;
    for (int i = tid; i < D; i += 256) { lnwf[i] = ldin(lnw, i, bf); lnbf[i] = ldin(lnb, i, bf); }

    // phase 0: split-K combine -> attnT
    int b_ = (int)(tok0 >> 12);
    int s_ = ((int)tok0 & 4095) >> 10;
    int tc0 = (int)tok0 & 1023;
    for (int idx = tid; idx < 32 * (ATS - DR); idx += 256) {
        int t = idx / (ATS - DR), f = idx % (ATS - DR);
        attnT[t * ATS + DR + f] = 0;
    }
    {
        int t = tid >> 3, h = tid & 7;
        const float* p1 = g_part + (((size_t)(b_ * NH + h)) * SPLIT + s_) * (size_t)(CHUNK * 20)
                        + (size_t)(tc0 + t) * 20;
        const float* p2 = p1 + (size_t)32 * SPLIT * CHUNK * 20;
        f32x4 a0 = *(const f32x4*)p1,        c0 = *(const f32x4*)p2;
        f32x4 a1 = *(const f32x4*)(p1 + 4),  c1 = *(const f32x4*)(p2 + 4);
        f32x4 a2 = *(const f32x4*)(p1 + 8),  c2 = *(const f32x4*)(p2 + 8);
        f32x4 a3 = *(const f32x4*)(p1 + 12), c3 = *(const f32x4*)(p2 + 12);
        f32x4 a4 = *(const f32x4*)(p1 + 16), c4 = *(const f32x4*)(p2 + 16);
        float inv = 1.f / (a4[2] + c4[2]);
        u16* dst = attnT + t * ATS + h * HD;
        #pragma unroll
        for (int d = 0; d < 4; ++d) {
            dst[d]      = f2bits((a0[d] + c0[d]) * inv);
            dst[4 + d]  = f2bits((a1[d] + c1[d]) * inv);
            dst[8 + d]  = f2bits((a2[d] + c2[d]) * inv);
            dst[12 + d] = f2bits((a3[d] + c3[d]) * inv);
        }
        dst[16] = f2bits((a4[0] + c4[0]) * inv);
        dst[17] = f2bits((a4[1] + c4[1]) * inv);
    }
    __syncthreads();

    // phase A: proj + residual -> t1f (LDS only)
    {
        bf16x8 areg0[5], areg1[5];
        const u16* a0 = attnT + l15 * ATS + quad * 8;
        const u16* a1 = attnT + (16 + l15) * ATS + quad * 8;
        #pragma unroll
        for (int ks = 0; ks < 5; ++ks) {
            areg0[ks] = *(const bf16x8*)(a0 + ks * 32);
            areg1[ks] = *(const bf16x8*)(a1 + ks * 32);
        }
        const int tab[5] = {0, 5, 10, 14, 18};
        for (int nt = tab[w]; nt < tab[w + 1]; ++nt) {
            f32x4 acc0 = {0.f, 0.f, 0.f, 0.f}, acc1 = {0.f, 0.f, 0.f, 0.f};
            const u16* bbase = g_pw + (size_t)(nt * 16 + l15) * ASTR + quad * 8;
            #pragma unroll
            for (int ks = 0; ks < 5; ++ks) {
                bf16x8 bfr = *(const bf16x8*)(bbase + ks * 32);
                acc0 = __builtin_amdgcn_mfma_f32_16x16x32_bf16(areg0[ks], bfr, acc0, 0, 0, 0);
                acc1 = __builtin_amdgcn_mfma_f32_16x16x32_bf16(areg1[ks], bfr, acc1, 0, 0, 0);
            }
            int o = nt * 16 + l15;
            float bias = ldin(proj_b, o, bf);
            #pragma unroll
            for (int r = 0; r < 4; ++r) {
                t1f[(quad * 4 + r) * 296 + o] =
                    f2bits(bits2f(g_t0[(tok0 + quad * 4 + r) * D + o]) + acc0[r] + bias);
                t1f[(16 + quad * 4 + r) * 296 + o] =
                    f2bits(bits2f(g_t0[(tok0 + 16 + quad * 4 + r) * D + o]) + acc1[r] + bias);
            }
        }
    }
    __syncthreads();
    {   // phase B: LN2 stats
        int tt = tid >> 3, p = tid & 7;
        const u32* src = (const u32*)&t1f[tt * 296 + p * 36];
        float s = 0.f, q = 0.f;
        #pragma unroll
        for (int j = 0; j < 18; ++j) {
            u32 v = src[j];
            float a = bits2f((u16)(v & 0xFFFF)), b = bits2f((u16)(v >> 16));
            s += a + b; q += a * a + b * b;
        }
        #pragma unroll
        for (int o = 1; o < 8; o <<= 1) { s += __shfl_xor(s, o); q += __shfl_xor(q, o); }
        if (p == 0) {
            float mu = s / D;
            smu[tt] = mu;
            srs[tt] = rsqrtf(q / D - mu * mu + EPS_);
        }
    }
    __syncthreads();
    for (int idx = tid; idx < 32 * 144; idx += 256) {   // phase C: normalize
        int t = idx / 144, dw = idx % 144;
        int f = 2 * dw;
        u32 v = *(const u32*)&t1f[t * 296 + f];
        float mu = smu[t], rs = srs[t];
        float a = (bits2f((u16)(v & 0xFFFF)) - mu) * rs * lnwf[f] + lnbf[f];
        float b = (bits2f((u16)(v >> 16)) - mu) * rs * lnwf[f + 1] + lnbf[f + 1];
        *(u32*)&xln[t * 296 + f] = (u32)f2bits(a) | ((u32)f2bits(b) << 16);
    }
    __syncthreads();
    {   // phase D: fc1 + relu -> hbuf (LDS)
        bf16x8 areg0[9], areg1[9];
        const u16* a0 = xln + l15 * 296 + quad * 8;
        const u16* a1 = xln + (16 + l15) * 296 + quad * 8;
        #pragma unroll
        for (int ks = 0; ks < 9; ++ks) {
            areg0[ks] = *(const bf16x8*)(a0 + ks * 32);
            areg1[ks] = *(const bf16x8*)(a1 + ks * 32);
        }
        const int tab2[5] = {0, 2, 4, 5, 6};
        for (int nt = tab2[w]; nt < tab2[w + 1]; ++nt) {
            f32x4 acc0 = {0.f, 0.f, 0.f, 0.f}, acc1 = {0.f, 0.f, 0.f, 0.f};
            const u16* bbase = g_f1w + (size_t)(nt * 16 + l15) * D + quad * 8;
            #pragma unroll
            for (int ks = 0; ks < 9; ++ks) {
                bf16x8 bfr = *(const bf16x8*)(bbase + ks * 32);
                acc0 = __builtin_amdgcn_mfma_f32_16x16x32_bf16(areg0[ks], bfr, acc0, 0, 0, 0);
                acc1 = __builtin_amdgcn_mfma_f32_16x16x32_bf16(areg1[ks], bfr, acc1, 0, 0, 0);
            }
            int o = nt * 16 + l15;
            float bias = (o < DH) ? ldin(fc1_b, o, bf) : 0.f;
            #pragma unroll
            for (int r = 0; r < 4; ++r) {
                hbuf[(quad * 4 + r) * HSTR + o] = f2bits(fmaxf(acc0[r] + bias, 0.f));
                hbuf[(16 + quad * 4 + r) * HSTR + o] = f2bits(fmaxf(acc1[r] + bias, 0.f));
            }
        }
    }
    __syncthreads();
    {   // phase E: fc2 + residual -> t2 bf16, staged in xln (dead after phase D frag reads)
        bf16x8 areg0[3], areg1[3];
        const u16* a0 = hbuf + l15 * HSTR + quad * 8;
        const u16* a1 = hbuf + (16 + l15) * HSTR + quad * 8;
        #pragma unroll
        for (int ks = 0; ks < 3; ++ks) {
            areg0[ks] = *(const bf16x8*)(a0 + ks * 32);
            areg1[ks] = *(const bf16x8*)(a1 + ks * 32);
        }
        const int tab[5] = {0, 5, 10, 14, 18};
        for (int nt = tab[w]; nt < tab[w + 1]; ++nt) {
            f32x4 acc0 = {0.f, 0.f, 0.f, 0.f}, acc1 = {0.f, 0.f, 0.f, 0.f};
            const u16* bbase = g_f2w + (size_t)(nt * 16 + l15) * HSTR + quad * 8;
            #pragma unroll
            for (int ks = 0; ks < 3; ++ks) {
                bf16x8 bfr = *(const bf16x8*)(bbase + ks * 32);
                acc0 = __builtin_amdgcn_mfma_f32_16x16x32_bf16(areg0[ks], bfr, acc0, 0, 0, 0);
                acc1 = __builtin_amdgcn_mfma_f32_16x16x32_bf16(areg1[ks], bfr, acc1, 0, 0, 0);
            }
            int o = nt * 16 + l15;
            float bias = ldin(fc2_b, o, bf);
            #pragma unroll
            for (int r = 0; r < 4; ++r) {
                xln[(quad * 4 + r) * 296 + o] =
                    f2bits(bits2f(t1f[(quad * 4 + r) * 296 + o]) + acc0[r] + bias);
                xln[(16 + quad * 4 + r) * 296 + o] =
                    f2bits(bits2f(t1f[(16 + quad * 4 + r) * 296 + o]) + acc1[r] + bias);
            }
        }
    }
    __syncthreads();
    {   // transposed u32-packed store to g_t2b
        int n0 = (int)(tok0 & 4095);
        for (int idx = tid; idx < D * 16; idx += 256) {
            int o = idx >> 4, tp = idx & 15;
            u32 v = (u32)xln[(2 * tp) * 296 + o] | ((u32)xln[(2 * tp + 1) * 296 + o] << 16);
            *(u32*)&g_t2b[((size_t)b_ * D + o) * NN + n0 + 2 * tp] = v;
        }
    }
}

// ---- fold -> out
__global__ void k_fold(void* __restrict__ out) {
    int bf = g_flag;
    int idx = blockIdx.x * blockDim.x + threadIdx.x;
    if (idx >= BB * CCH * HH * WW) return;
    int xx = idx % WW;
    int y = (idx / WW) % HH;
    int c = (idx / (WW * HH)) % CCH;
    int b = idx / (WW * HH * CCH);
    const u16* base = g_t2b + ((size_t)b * D + c * 9) * NN;
    float s = 0.f;
    #pragma unroll
    for (int i = 0; i < 3; ++i) {
        int sy = y + 1 - i;
        if (sy < 0 || sy >= HH) continue;
        #pragma unroll
        for (int j = 0; j < 3; ++j) {
            int sx = xx + 1 - j;
            if (sx < 0 || sx >= WW) continue;
            s += bits2f(base[(size_t)(i * 3 + j) * NN + sy * WW + sx]);
        }
    }
    if (bf) ((bf16*)out)[idx] = __float2bfloat16(s);
    else    ((float*)out)[idx] = s;
}

extern "C" void kernel_launch(void* const* d_in, const int* in_sizes, int n_in,
                              void* d_out, int out_size, void* d_ws, size_t ws_size,
                              hipStream_t stream) {
    const void* x        = d_in[0];
    const void* ln1_w    = d_in[1];
    const void* ln1_b    = d_in[2];
    const void* reduce_w = d_in[3];
    const void* qkv_w    = d_in[4];
    const void* proj_w   = d_in[5];
    const void* proj_b   = d_in[6];
    const void* ln2_w    = d_in[7];
    const void* ln2_b    = d_in[8];
    const void* fc1_w    = d_in[9];
    const void* fc1_b    = d_in[10];
    const void* fc2_w    = d_in[11];
    const void* fc2_b    = d_in[12];

    k_prep     <<<DQ + RSB + PATCHB, 256, 0, stream>>>(x, qkv_w, reduce_w, proj_w, fc1_w, fc2_w);
    k_ln_qkv   <<<BB * NN / 32, 256, 0, stream>>>(ln1_w, ln1_b);
    k_attn     <<<2 * BB * NH * SPLIT * 8, 128, 0, stream>>>();
    k_proj_mlp <<<BB * NN / 32, 256, 0, stream>>>(proj_b, ln2_w, ln2_b, fc1_b, fc2_b);
    k_fold     <<<(BB * CCH * HH * WW + 255) / 256, 256, 0, stream>>>(d_out);
}